// Round 14
// baseline (192.746 us; speedup 1.0000x reference)
//
#include <hip/hip_runtime.h>
#include <hip/hip_bf16.h>
#include <cmath>
#include <stdint.h>

using bf16 = __hip_bfloat16;
typedef __attribute__((ext_vector_type(8))) short bf16x8;
typedef __attribute__((ext_vector_type(4))) float f32x4;

// R=128, N=256, B=1, E=512, H=8, D=64, M=4
constexpr long HS = 2097152;  // per-head Vj size: (R*D) * N = 8192*256

// async 16B global -> LDS (linear dest: wave base + lane*16)
__device__ __forceinline__ void gload16(const bf16* g, bf16* l)
{
  __builtin_amdgcn_global_load_lds(
      (const __attribute__((address_space(1))) void*)g,
      (__attribute__((address_space(3))) void*)l,
      16, 0, 0);
}

// T2 swizzle: chunk c stores global slot (c&3)^((c>>3)&3) at linear slot (c&3).
// Read side: lane reads element offset ((lane>>4)^((lane>>1)&3))*8 of its row.
__device__ __forceinline__ int swsrc(int c) { return (((c & 3) ^ ((c >> 3) & 3)) * 8); }

// ---------------- x fp32 -> bf16 (once) ----------------
__global__ __launch_bounds__(256)
void k_convert_x(const float* __restrict__ x, bf16* __restrict__ xb)
{
  const long idx = (long)blockIdx.x * 256 + threadIdx.x;  // x8 elems
  const float4 f0 = *(const float4*)&x[idx * 8];
  const float4 f1 = *(const float4*)&x[idx * 8 + 4];
  alignas(16) bf16 t[8] = {
    __float2bfloat16(f0.x), __float2bfloat16(f0.y),
    __float2bfloat16(f0.z), __float2bfloat16(f0.w),
    __float2bfloat16(f1.x), __float2bfloat16(f1.y),
    __float2bfloat16(f1.z), __float2bfloat16(f1.w)};
  *(uint4*)&xb[idx * 8] = *(const uint4*)t;
}

// ---------------- weight transpose: WT[n][k] = W[k][n] ----------------
__global__ __launch_bounds__(256)
void k_prep_w(const float* __restrict__ Wq, const float* __restrict__ Wk,
              const float* __restrict__ Wv, const float* __restrict__ Wo,
              bf16* __restrict__ WT, float scaling)
{
  const int sel = blockIdx.z;
  const float* W = sel == 0 ? Wq : sel == 1 ? Wk : sel == 2 ? Wv : Wo;
  const float sc = sel == 0 ? scaling : 1.0f;
  const int k0 = blockIdx.x * 64, n0 = blockIdx.y * 64;
  __shared__ float tile[64][68];
  const int tid = threadIdx.x;
  #pragma unroll
  for (int it = 0; it < 4; it++) {
    const int c = tid + it * 256;
    const int kk = c >> 4, nn4 = (c & 15) * 4;
    const float4 v = *(const float4*)&W[(long)(k0 + kk) * 512 + n0 + nn4];
    tile[kk][nn4] = v.x; tile[kk][nn4 + 1] = v.y;
    tile[kk][nn4 + 2] = v.z; tile[kk][nn4 + 3] = v.w;
  }
  __syncthreads();
  #pragma unroll
  for (int it = 0; it < 2; it++) {
    const int c = tid + it * 256;
    const int nn = c >> 3, k8 = (c & 7) * 8;
    alignas(16) bf16 t[8];
    #pragma unroll
    for (int jj = 0; jj < 8; jj++) t[jj] = __float2bfloat16(tile[k8 + jj][nn] * sc);
    *(uint4*)&WT[(long)(sel * 512 + n0 + nn) * 512 + k0 + k8] = *(const uint4*)t;
  }
}

__global__ void k_prep_small(const float* __restrict__ bq, const float* __restrict__ bk,
                             const float* __restrict__ bv, const float* __restrict__ bo,
                             const float* __restrict__ Wq1, const float* __restrict__ Wk1,
                             float* __restrict__ bias_all, float* __restrict__ u, float scaling)
{
  const int idx = blockIdx.x * 256 + threadIdx.x;  // 2048
  const int s2 = idx >> 9, n2 = idx & 511;
  const float* b = s2 == 0 ? bq : s2 == 1 ? bk : s2 == 2 ? bv : bo;
  bias_all[idx] = b[n2] * (s2 == 0 ? scaling : 1.0f);
  if (idx < 64) {
    float s = 0.0f;
    #pragma unroll
    for (int c = 0; c < 8; c++) s += Wq1[idx * 8 + c] * Wk1[c];
    u[idx] = s;
  }
}

// ---------------- QKV projection: 256x256 tile, 8 waves, 4-buf deep pipeline ----------------
__global__ __launch_bounds__(512, 2)
void gemm_qkv(const bf16* __restrict__ xb, const bf16* __restrict__ WT,
              const float* __restrict__ bias_all,
              bf16* __restrict__ Qn, bf16* __restrict__ Kn, bf16* __restrict__ Vj)
{
  __shared__ __align__(16) unsigned short smem[65536];   // 128 KB: As 4x8192, Bs 4x8192
  bf16* As = (bf16*)smem;
  bf16* Bs = (bf16*)smem + 32768;
  const int tid = threadIdx.x, lane = tid & 63;
  const int wid = tid >> 6, wr = wid >> 2, wc = wid & 3;  // 2(m) x 4(n)
  const int lr = lane & 15;
  const int lkx = ((lane >> 4) ^ ((lane >> 1) & 3)) * 8;  // swizzled read offset
  // XCD-aware bijective swizzle (768 = 8 * 96)
  const int flat = ((int)blockIdx.x & 7) * 96 + ((int)blockIdx.x >> 3);
  const int m0 = (flat / 6) * 256, nt = flat % 6, n0 = nt * 256;
  const int c1 = tid + 512;
  const int ra0 = tid >> 2, ra1 = c1 >> 2;   // rows 0..255
  const int ps0 = swsrc(tid), ps1 = swsrc(c1);
  f32x4 acc[8][4] = {};

  auto stage = [&](int b, int k0) {
    gload16(&xb[(long)(m0 + ra0) * 512 + k0 + ps0], &As[b * 8192 + tid * 8]);
    gload16(&xb[(long)(m0 + ra1) * 512 + k0 + ps1], &As[b * 8192 + c1 * 8]);
    gload16(&WT[(long)(n0 + ra0) * 512 + k0 + ps0], &Bs[b * 8192 + tid * 8]);
    gload16(&WT[(long)(n0 + ra1) * 512 + k0 + ps1], &Bs[b * 8192 + c1 * 8]);
  };

  stage(0, 0);
  stage(1, 32);
  stage(2, 64);

  for (int t = 0; t < 16; ++t) {
    const int cur = t & 3;
    if (t < 13) stage((t + 3) & 3, (t + 3) * 32);
    if (t == 0) {
      asm volatile("s_waitcnt vmcnt(12)" ::: "memory");
      __builtin_amdgcn_s_barrier();
    }
    bf16x8 af[8], bfr[4];
    #pragma unroll
    for (int n = 0; n < 4; n++)
      bfr[n] = *(const bf16x8*)&Bs[cur * 8192 + (wc * 64 + n * 16 + lr) * 32 + lkx];
    #pragma unroll
    for (int m = 0; m < 8; m++)
      af[m] = *(const bf16x8*)&As[cur * 8192 + (wr * 128 + m * 16 + lr) * 32 + lkx];
    __builtin_amdgcn_s_setprio(1);
    #pragma unroll
    for (int m = 0; m < 8; m++)
      #pragma unroll
      for (int n = 0; n < 4; n++)
        acc[m][n] = __builtin_amdgcn_mfma_f32_16x16x32_bf16(af[m], bfr[n], acc[m][n], 0, 0, 0);
    __builtin_amdgcn_s_setprio(0);
    if (t < 13)       asm volatile("s_waitcnt vmcnt(8)" ::: "memory");
    else if (t == 13) asm volatile("s_waitcnt vmcnt(4)" ::: "memory");
    else if (t == 14) asm volatile("s_waitcnt vmcnt(0)" ::: "memory");
    __builtin_amdgcn_s_barrier();
  }

  const int er = (lane >> 4) * 4, ec = lane & 15;
  if (nt < 4) {
    bf16* dst = (nt < 2) ? Qn : Kn;
    const int cb = (nt < 2) ? n0 : n0 - 512;
    #pragma unroll
    for (int m = 0; m < 8; m++) {
      const int row0 = m0 + wr * 128 + m * 16 + er;
      #pragma unroll
      for (int n = 0; n < 4; n++) {
        const int cw = wc * 64 + n * 16 + ec;
        const float bv = bias_all[n0 + cw];
        #pragma unroll
        for (int q = 0; q < 4; q++)
          dst[(long)(row0 + q) * 512 + cb + cw] = __float2bfloat16(acc[m][n][q] + bv);
      }
    }
  } else {
    // V tile: 4 passes over hd-quadrants; LDS transpose vt[64][264]; coalesced Vj stores
    bf16* vt = (bf16*)smem;
    const int r = m0 >> 8;
    const int hdbase = (nt - 4) * 256;
    #pragma unroll 1
    for (int p = 0; p < 4; ++p) {
      __syncthreads();
      if (wc == p) {
        #pragma unroll
        for (int m = 0; m < 8; m++) {
          const int rt0 = wr * 128 + m * 16 + er;
          #pragma unroll
          for (int n = 0; n < 4; n++) {
            const int ct = n * 16 + ec;
            const float bv = bias_all[n0 + p * 64 + ct];
            #pragma unroll
            for (int q = 0; q < 4; q++)
              vt[ct * 264 + rt0 + q] = __float2bfloat16(acc[m][n][q] + bv);
          }
        }
      }
      __syncthreads();
      #pragma unroll
      for (int cc = 0; cc < 4; cc++) {
        const int c = cc * 512 + tid;
        const int hl = c >> 5, tok8 = (c & 31) * 8;
        const uint4 v = *(const uint4*)&vt[hl * 264 + tok8];
        const int hd = hdbase + p * 64 + hl;
        const int h = hd >> 6, d = hd & 63;
        *(uint4*)&Vj[(long)h * HS + (long)(r * 64 + d) * 256 + tok8] = v;
      }
    }
  }
}

// ---------------- logits MERGED: each block computes head-acc AND u-scaled acc ----------------
// z in [0,64): h = z>>3, ks = z&7 (splitK=8, K-slice 1024, 32 iters). Staging shared;
// u-scaled A fragment derived in registers (d = (kk&1)*32 + lkx + j). 4-buf counted pipeline.
// Outputs: slab z (head logits partial), slab 64+z (MLP-branch partial).
__global__ __launch_bounds__(256)
void gemm_logits(const bf16* __restrict__ Qn, const bf16* __restrict__ Kn,
                 const float* __restrict__ u, float* __restrict__ part)
{
  __shared__ bf16 As[4][128 * 32];
  __shared__ bf16 Bs[4][128 * 32];
  __shared__ float us[64];
  const int tid = threadIdx.x, lane = tid & 63;
  const int wid = tid >> 6, wr = wid >> 1, wc = wid & 1;
  const int lr = lane & 15;
  const int lkx = ((lane >> 4) ^ ((lane >> 1) & 3)) * 8;
  const int z = blockIdx.z, h = z >> 3, ks = z & 7;
  const int m0 = blockIdx.y * 128, n0 = blockIdx.x * 128;
  if (tid < 64) us[tid] = u[tid];
  __syncthreads();
  float ufa[8], ufb[8];   // u[d] for this lane's fragment elems; d = sel*32 + lkx + j
  #pragma unroll
  for (int j = 0; j < 8; j++) { ufa[j] = us[lkx + j]; ufb[j] = us[32 + lkx + j]; }
  const int c1 = tid + 256;
  const int ra0 = tid >> 2, ra1 = c1 >> 2;
  const int ps = swsrc(tid);
  f32x4 acc[4][4] = {}, accu[4][4] = {};

  auto stage = [&](int b, int kk) {
    const int gk = ks * 1024 + kk * 32;
    const int r = gk >> 6, d0 = gk & 63;
    const long ab = (long)(r * 256 + m0) * 512 + h * 64 + d0;
    const long bb = (long)(r * 256 + n0) * 512 + h * 64 + d0;
    gload16(&Qn[ab + (long)ra0 * 512 + ps], &As[b][tid * 8]);
    gload16(&Qn[ab + (long)ra1 * 512 + ps], &As[b][c1 * 8]);
    gload16(&Kn[bb + (long)ra0 * 512 + ps], &Bs[b][tid * 8]);
    gload16(&Kn[bb + (long)ra1 * 512 + ps], &Bs[b][c1 * 8]);
  };

  stage(0, 0);
  stage(1, 1);
  stage(2, 2);

  for (int kk = 0; kk < 32; ++kk) {
    const int cur = kk & 3;
    if (kk < 29) stage((kk + 3) & 3, kk + 3);
    if (kk == 0) {
      asm volatile("s_waitcnt vmcnt(12)" ::: "memory");
      __builtin_amdgcn_s_barrier();
    }
    const bool odd = (kk & 1) != 0;   // d0 = (kk&1)*32
    bf16x8 af[4], bfr[4], afu[4];
    #pragma unroll
    for (int m = 0; m < 4; m++)
      af[m] = *(const bf16x8*)&As[cur][(wr * 64 + m * 16 + lr) * 32 + lkx];
    #pragma unroll
    for (int n = 0; n < 4; n++)
      bfr[n] = *(const bf16x8*)&Bs[cur][(wc * 64 + n * 16 + lr) * 32 + lkx];
    #pragma unroll
    for (int m = 0; m < 4; m++) {
      #pragma unroll
      for (int j = 0; j < 8; j++) {
        const unsigned short a_ = (unsigned short)af[m][j];
        const float f = __bfloat162float(*(const bf16*)&a_) * (odd ? ufb[j] : ufa[j]);
        const bf16 b_ = __float2bfloat16(f);
        afu[m][j] = *(const short*)&b_;
      }
    }
    __builtin_amdgcn_s_setprio(1);
    #pragma unroll
    for (int m = 0; m < 4; m++)
      #pragma unroll
      for (int n = 0; n < 4; n++)
        acc[m][n] = __builtin_amdgcn_mfma_f32_16x16x32_bf16(af[m], bfr[n], acc[m][n], 0, 0, 0);
    #pragma unroll
    for (int m = 0; m < 4; m++)
      #pragma unroll
      for (int n = 0; n < 4; n++)
        accu[m][n] = __builtin_amdgcn_mfma_f32_16x16x32_bf16(afu[m], bfr[n], accu[m][n], 0, 0, 0);
    __builtin_amdgcn_s_setprio(0);
    if (kk < 29)       asm volatile("s_waitcnt vmcnt(8)" ::: "memory");
    else if (kk == 29) asm volatile("s_waitcnt vmcnt(4)" ::: "memory");
    else if (kk == 30) asm volatile("s_waitcnt vmcnt(0)" ::: "memory");
    __builtin_amdgcn_s_barrier();
  }

  float* C  = part + (long)z * 65536;
  float* Cu = part + (long)(64 + z) * 65536;
  const int er = (lane >> 4) * 4, ec = lane & 15;
  #pragma unroll
  for (int m = 0; m < 4; m++)
    #pragma unroll
    for (int n = 0; n < 4; n++) {
      const int col = n0 + wc * 64 + n * 16 + ec;
      #pragma unroll
      for (int q = 0; q < 4; q++) {
        const long idx = (long)(m0 + wr * 64 + m * 16 + er + q) * 256 + col;
        C[idx]  = acc[m][n][q];
        Cu[idx] = accu[m][n][q];
      }
    }
}

// ---------------- ctx GEMM: A=Pb[h] (i x j), B=Vj[h] ((r,d) x j), K=256, counted 3-buf ----------------
__global__ __launch_bounds__(256)
void gemm_ctx(const bf16* __restrict__ Pb, const bf16* __restrict__ Vj,
              bf16* __restrict__ ctxb)
{
  __shared__ bf16 As[3][128 * 32];
  __shared__ bf16 Bs[3][128 * 32];
  const int tid = threadIdx.x, lane = tid & 63;
  const int wid = tid >> 6, wr = wid >> 1, wc = wid & 1;
  const int lr = lane & 15;
  const int lkx = ((lane >> 4) ^ ((lane >> 1) & 3)) * 8;
  const int m0 = blockIdx.y * 128, n0 = blockIdx.x * 128, h = blockIdx.z;
  const bf16* A = Pb + (long)h * 65536;
  const bf16* B = Vj + (long)h * HS;
  const int c1 = tid + 256;
  const int ra0 = tid >> 2, ra1 = c1 >> 2;
  const int ps = swsrc(tid);
  f32x4 acc[4][4] = {};

  auto stage = [&](int b, int k0) {
    gload16(&A[(long)(m0 + ra0) * 256 + k0 + ps], &As[b][tid * 8]);
    gload16(&A[(long)(m0 + ra1) * 256 + k0 + ps], &As[b][c1 * 8]);
    gload16(&B[(long)(n0 + ra0) * 256 + k0 + ps], &Bs[b][tid * 8]);
    gload16(&B[(long)(n0 + ra1) * 256 + k0 + ps], &Bs[b][c1 * 8]);
  };

  stage(0, 0);
  stage(1, 32);

  for (int t = 0; t < 8; ++t) {
    const int cur = t % 3;
    if (t < 6) {
      stage((t + 2) % 3, (t + 2) * 32);
      asm volatile("s_waitcnt vmcnt(8)" ::: "memory");
    } else if (t == 6) {
      asm volatile("s_waitcnt vmcnt(4)" ::: "memory");
    } else {
      asm volatile("s_waitcnt vmcnt(0)" ::: "memory");
    }
    __builtin_amdgcn_s_barrier();
    bf16x8 af[4], bfr[4];
    #pragma unroll
    for (int m = 0; m < 4; m++)
      af[m] = *(const bf16x8*)&As[cur][(wr * 64 + m * 16 + lr) * 32 + lkx];
    #pragma unroll
    for (int n = 0; n < 4; n++)
      bfr[n] = *(const bf16x8*)&Bs[cur][(wc * 64 + n * 16 + lr) * 32 + lkx];
    #pragma unroll
    for (int m = 0; m < 4; m++)
      #pragma unroll
      for (int n = 0; n < 4; n++)
        acc[m][n] = __builtin_amdgcn_mfma_f32_16x16x32_bf16(af[m], bfr[n], acc[m][n], 0, 0, 0);
    __builtin_amdgcn_s_barrier();
  }

  const int er = (lane >> 4) * 4, ec = lane & 15;
  #pragma unroll
  for (int m = 0; m < 4; m++) {
    const int i0 = m0 + wr * 64 + m * 16 + er;
    #pragma unroll
    for (int n = 0; n < 4; n++) {
      const int col = n0 + wc * 64 + n * 16 + ec;   // col = r*64 + d
      const int rr = col >> 6, dd = col & 63;
      #pragma unroll
      for (int q = 0; q < 4; q++)
        ctxb[(long)(rr * 256 + i0 + q) * 512 + h * 64 + dd] = __float2bfloat16(acc[m][n][q]);
    }
  }
}

// ---------------- output projection: 3-buffer counted-vmcnt, RAW barriers ----------------
__global__ __launch_bounds__(512)
void gemm_outp(const bf16* __restrict__ A, const bf16* __restrict__ B,
               float* __restrict__ C, const float* __restrict__ bias)
{
  __shared__ bf16 As[3][128 * 32];
  __shared__ bf16 Bs[3][256 * 32];
  const int tid = threadIdx.x, lane = tid & 63, wid = tid >> 6;
  const int wr = wid >> 2, wc = wid & 3;
  const int lr = lane & 15;
  const int lkx = ((lane >> 4) ^ ((lane >> 1) & 3)) * 8;
  const int m0 = blockIdx.y * 128, n0 = blockIdx.x * 256;
  const int ra = tid >> 2;
  const int cb1 = tid + 512;
  const int rb0 = tid >> 2, rb1 = cb1 >> 2;
  const int ps = swsrc(tid);
  f32x4 acc[4][4] = {};

  auto stage = [&](int b, int k0) {
    gload16(&A[(long)(m0 + ra) * 512 + k0 + ps], &As[b][tid * 8]);
    gload16(&B[(long)(n0 + rb0) * 512 + k0 + ps], &Bs[b][tid * 8]);
    gload16(&B[(long)(n0 + rb1) * 512 + k0 + ps], &Bs[b][cb1 * 8]);
  };

  stage(0, 0);
  stage(1, 32);

  for (int t = 0; t < 16; ++t) {
    const int cur = t % 3;
    if (t < 14) {
      stage((t + 2) % 3, (t + 2) * 32);
      asm volatile("s_waitcnt vmcnt(6)" ::: "memory");
    } else if (t == 14) {
      asm volatile("s_waitcnt vmcnt(3)" ::: "memory");
    } else {
      asm volatile("s_waitcnt vmcnt(0)" ::: "memory");
    }
    __builtin_amdgcn_s_barrier();
    bf16x8 af[4], bfr[4];
    #pragma unroll
    for (int m = 0; m < 4; m++)
      af[m] = *(const bf16x8*)&As[cur][(wr * 64 + m * 16 + lr) * 32 + lkx];
    #pragma unroll
    for (int n = 0; n < 4; n++)
      bfr[n] = *(const bf16x8*)&Bs[cur][(wc * 64 + n * 16 + lr) * 32 + lkx];
    #pragma unroll
    for (int m = 0; m < 4; m++)
      #pragma unroll
      for (int n = 0; n < 4; n++)
        acc[m][n] = __builtin_amdgcn_mfma_f32_16x16x32_bf16(af[m], bfr[n], acc[m][n], 0, 0, 0);
    __builtin_amdgcn_s_barrier();
  }

  const int er = (lane >> 4) * 4, ec = lane & 15;
  #pragma unroll
  for (int m = 0; m < 4; m++) {
    const int row0 = m0 + wr * 64 + m * 16 + er;
    #pragma unroll
    for (int n = 0; n < 4; n++) {
      const int col = n0 + wc * 64 + n * 16 + ec;
      const float bv = bias[col];
      #pragma unroll
      for (int q = 0; q < 4; q++)
        C[(long)(row0 + q) * 512 + col] = acc[m][n][q] + bv;
    }
  }
}

// ---------------- network-bias branch (u-slabs 64..127) ----------------
__global__ void k_bias(const float* __restrict__ part, const float* __restrict__ network,
                       const float* __restrict__ bq1, const float* __restrict__ Wk1,
                       float* __restrict__ net_bias)
{
  const int i = blockIdx.x, j = threadIdx.x;
  float c1 = 0.0f;
  #pragma unroll
  for (int c = 0; c < 8; c++) c1 += bq1[c] * Wk1[c];
  float s1 = 0.0f;
  const long ij = i * 256 + j;
  #pragma unroll
  for (int s = 64; s < 128; s++) s1 += part[(long)s * 65536 + ij];
  s1 = 0.125f * s1 + c1;
  const float4 nw = *(const float4*)&network[ij * 4];
  const float a0 = nw.x * s1, a1 = nw.y * s1, a2 = nw.z * s1, a3 = nw.w * s1;
  const float mx = fmaxf(fmaxf(a0, a1), fmaxf(a2, a3));
  const float e0 = expf(a0 - mx), e1 = expf(a1 - mx), e2 = expf(a2 - mx), e3 = expf(a3 - mx);
  const float inv = 1.0f / (e0 + e1 + e2 + e3);
  net_bias[ij] = (nw.x * e0 + nw.y * e1 + nw.z * e2 + nw.w * e3) * inv;
}

// ---------------- row softmax (sums 8 split-K partials), eye mask ----------------
__global__ void k_softmax(const float* __restrict__ part, const float* __restrict__ net_bias,
                          const float* __restrict__ l, float* __restrict__ out_probs,
                          bf16* __restrict__ Pb, float* __restrict__ out_l)
{
  const int i = blockIdx.x, h = blockIdx.y, j = threadIdx.x;
  const long ij = i * 256 + j;
  float w = 0.0f;
  #pragma unroll
  for (int ks = 0; ks < 8; ks++) w += part[(long)(h * 8 + ks) * 65536 + ij];
  w += l[h] * net_bias[ij];
  if (j == i) w = -1e9f;
  float m = w;
  #pragma unroll
  for (int o = 32; o; o >>= 1) m = fmaxf(m, __shfl_xor(m, o));
  __shared__ float red[4], red2[4];
  if ((j & 63) == 0) red[j >> 6] = m;
  __syncthreads();
  m = fmaxf(fmaxf(red[0], red[1]), fmaxf(red[2], red[3]));
  const float e = expf(w - m);
  float s = e;
  #pragma unroll
  for (int o = 32; o; o >>= 1) s += __shfl_xor(s, o);
  if ((j & 63) == 0) red2[j >> 6] = s;
  __syncthreads();
  s = red2[0] + red2[1] + red2[2] + red2[3];
  const float p = e / s;
  out_probs[(long)h * 65536 + ij] = p;
  Pb[(long)h * 65536 + ij] = __float2bfloat16(p);
  if (h == 0 && i == 0 && j < 8) out_l[j] = l[j];
}

extern "C" void kernel_launch(void* const* d_in, const int* in_sizes, int n_in,
                              void* d_out, int out_size, void* d_ws, size_t ws_size,
                              hipStream_t stream)
{
  const float* x   = (const float*)d_in[0];
  const float* net = (const float*)d_in[1];
  const float* Wq  = (const float*)d_in[2];
  const float* bq  = (const float*)d_in[3];
  const float* Wk  = (const float*)d_in[4];
  const float* bk  = (const float*)d_in[5];
  const float* Wv  = (const float*)d_in[6];
  const float* bv  = (const float*)d_in[7];
  const float* Wo  = (const float*)d_in[8];
  const float* bo  = (const float*)d_in[9];
  const float* Wq1 = (const float*)d_in[10];
  const float* bq1 = (const float*)d_in[11];
  const float* Wk1 = (const float*)d_in[12];
  const float* l   = (const float*)d_in[14];
  float* out = (float*)d_out;

  // d_out scratch: Qn [0,32MB), Kn [32,64MB) — dead before gemm_outp writes out.
  bf16* Qn = (bf16*)d_out;
  bf16* Kn = Qn + 16777216;

  char* ws = (char*)d_ws;
  size_t off = 0;
  auto alloc = [&](size_t bytes) { char* p = ws + off; off += (bytes + 255) & ~255ULL; return p; };
  bf16*  WT       = (bf16*)alloc(2048ULL * 512 * 2);    //  2 MB
  float* bias_all = (float*)alloc(2048 * 4);
  float* u        = (float*)alloc(64 * 4);
  bf16*  xb       = (bf16*)alloc(16777216ULL * 2);      // 32 MB -> part -> ctxb
  bf16*  Vj       = (bf16*)alloc(16777216ULL * 2);      // 32 MB (transposed V from qkv)
  float* net_bias = (float*)alloc(65536ULL * 4);        // 256 KB
  bf16*  Pb       = (bf16*)alloc(8ULL * 65536 * 2);     //  1 MB  (total ~67.5 MB)
  float* part     = (float*)xb;   // xb dead after gemm_qkv; 128 x 256KB = 32 MB exact
  bf16*  ctxb     = xb;           // part dead after k_bias/k_softmax

  const float scaling = (float)(0.125 / sqrt(128.0));  // D^-0.5 / sqrt(R)

  k_convert_x<<<8192, 256, 0, stream>>>(x, xb);
  k_prep_w<<<dim3(8, 8, 4), 256, 0, stream>>>(Wq, Wk, Wv, Wo, WT, scaling);
  k_prep_small<<<8, 256, 0, stream>>>(bq, bk, bv, bo, Wq1, Wk1, bias_all, u, scaling);

  gemm_qkv<<<768, 512, 0, stream>>>(xb, WT, bias_all, Qn, Kn, Vj);

  // merged: slabs 0..63 = head-logit partials (h*8+ks), slabs 64..127 = MLP partials
  gemm_logits<<<dim3(2, 2, 64), 256, 0, stream>>>(Qn, Kn, u, part);

  k_bias<<<256, 256, 0, stream>>>(part, net, bq1, Wk1, net_bias);
  k_softmax<<<dim3(256, 8, 1), 256, 0, stream>>>(part, net_bias, l,
                                                 out + 16777216, Pb, out + 17301504);

  gemm_ctx<<<dim3(64, 2, 8), 256, 0, stream>>>(Pb, Vj, ctxb);

  gemm_outp<<<dim3(2, 256, 1), 512, 0, stream>>>(ctxb, WT + 1536 * 512, out, bias_all + 1536);
}

// Round 15
// 189.912 us; speedup vs baseline: 1.0149x; 1.0149x over previous
//
#include <hip/hip_runtime.h>
#include <hip/hip_bf16.h>
#include <cmath>
#include <stdint.h>

using bf16 = __hip_bfloat16;
typedef __attribute__((ext_vector_type(8))) short bf16x8;
typedef __attribute__((ext_vector_type(4))) float f32x4;

// R=128, N=256, B=1, E=512, H=8, D=64, M=4
constexpr long HS = 2097152;  // per-head Vj size: (R*D) * N = 8192*256

// async 16B global -> LDS (linear dest: wave base + lane*16)
__device__ __forceinline__ void gload16(const bf16* g, bf16* l)
{
  __builtin_amdgcn_global_load_lds(
      (const __attribute__((address_space(1))) void*)g,
      (__attribute__((address_space(3))) void*)l,
      16, 0, 0);
}

// T2 swizzle: chunk c stores global slot (c&3)^((c>>3)&3) at linear slot (c&3).
// Read side: lane reads element offset ((lane>>4)^((lane>>1)&3))*8 of its row,
// which delivers LOGICAL chunk (lane>>4) (swizzle cancels against row bits).
__device__ __forceinline__ int swsrc(int c) { return (((c & 3) ^ ((c >> 3) & 3)) * 8); }

// ---------------- x fp32 -> bf16 (once) ----------------
__global__ __launch_bounds__(256)
void k_convert_x(const float* __restrict__ x, bf16* __restrict__ xb)
{
  const long idx = (long)blockIdx.x * 256 + threadIdx.x;  // x8 elems
  const float4 f0 = *(const float4*)&x[idx * 8];
  const float4 f1 = *(const float4*)&x[idx * 8 + 4];
  alignas(16) bf16 t[8] = {
    __float2bfloat16(f0.x), __float2bfloat16(f0.y),
    __float2bfloat16(f0.z), __float2bfloat16(f0.w),
    __float2bfloat16(f1.x), __float2bfloat16(f1.y),
    __float2bfloat16(f1.z), __float2bfloat16(f1.w)};
  *(uint4*)&xb[idx * 8] = *(const uint4*)t;
}

// ---------------- weight transpose: WT[n][k] = W[k][n] ----------------
__global__ __launch_bounds__(256)
void k_prep_w(const float* __restrict__ Wq, const float* __restrict__ Wk,
              const float* __restrict__ Wv, const float* __restrict__ Wo,
              bf16* __restrict__ WT, float scaling)
{
  const int sel = blockIdx.z;
  const float* W = sel == 0 ? Wq : sel == 1 ? Wk : sel == 2 ? Wv : Wo;
  const float sc = sel == 0 ? scaling : 1.0f;
  const int k0 = blockIdx.x * 64, n0 = blockIdx.y * 64;
  __shared__ float tile[64][68];
  const int tid = threadIdx.x;
  #pragma unroll
  for (int it = 0; it < 4; it++) {
    const int c = tid + it * 256;
    const int kk = c >> 4, nn4 = (c & 15) * 4;
    const float4 v = *(const float4*)&W[(long)(k0 + kk) * 512 + n0 + nn4];
    tile[kk][nn4] = v.x; tile[kk][nn4 + 1] = v.y;
    tile[kk][nn4 + 2] = v.z; tile[kk][nn4 + 3] = v.w;
  }
  __syncthreads();
  #pragma unroll
  for (int it = 0; it < 2; it++) {
    const int c = tid + it * 256;
    const int nn = c >> 3, k8 = (c & 7) * 8;
    alignas(16) bf16 t[8];
    #pragma unroll
    for (int jj = 0; jj < 8; jj++) t[jj] = __float2bfloat16(tile[k8 + jj][nn] * sc);
    *(uint4*)&WT[(long)(sel * 512 + n0 + nn) * 512 + k0 + k8] = *(const uint4*)t;
  }
}

__global__ void k_prep_small(const float* __restrict__ bq, const float* __restrict__ bk,
                             const float* __restrict__ bv, const float* __restrict__ bo,
                             const float* __restrict__ Wq1, const float* __restrict__ Wk1,
                             float* __restrict__ bias_all, float* __restrict__ u, float scaling)
{
  const int idx = blockIdx.x * 256 + threadIdx.x;  // 2048
  const int s2 = idx >> 9, n2 = idx & 511;
  const float* b = s2 == 0 ? bq : s2 == 1 ? bk : s2 == 2 ? bv : bo;
  bias_all[idx] = b[n2] * (s2 == 0 ? scaling : 1.0f);
  if (idx < 64) {
    float s = 0.0f;
    #pragma unroll
    for (int c = 0; c < 8; c++) s += Wq1[idx * 8 + c] * Wk1[c];
    u[idx] = s;
  }
}

// ---------------- QKV projection: 256x256 tile, 8 waves, 4-buf deep pipeline ----------------
__global__ __launch_bounds__(512, 2)
void gemm_qkv(const bf16* __restrict__ xb, const bf16* __restrict__ WT,
              const float* __restrict__ bias_all,
              bf16* __restrict__ Qn, bf16* __restrict__ Kn, bf16* __restrict__ Vj)
{
  __shared__ __align__(16) unsigned short smem[65536];   // 128 KB: As 4x8192, Bs 4x8192
  bf16* As = (bf16*)smem;
  bf16* Bs = (bf16*)smem + 32768;
  const int tid = threadIdx.x, lane = tid & 63;
  const int wid = tid >> 6, wr = wid >> 2, wc = wid & 3;  // 2(m) x 4(n)
  const int lr = lane & 15;
  const int lkx = ((lane >> 4) ^ ((lane >> 1) & 3)) * 8;  // swizzled read offset
  // XCD-aware bijective swizzle (768 = 8 * 96)
  const int flat = ((int)blockIdx.x & 7) * 96 + ((int)blockIdx.x >> 3);
  const int m0 = (flat / 6) * 256, nt = flat % 6, n0 = nt * 256;
  const int c1 = tid + 512;
  const int ra0 = tid >> 2, ra1 = c1 >> 2;   // rows 0..255
  const int ps0 = swsrc(tid), ps1 = swsrc(c1);
  f32x4 acc[8][4] = {};

  auto stage = [&](int b, int k0) {
    gload16(&xb[(long)(m0 + ra0) * 512 + k0 + ps0], &As[b * 8192 + tid * 8]);
    gload16(&xb[(long)(m0 + ra1) * 512 + k0 + ps1], &As[b * 8192 + c1 * 8]);
    gload16(&WT[(long)(n0 + ra0) * 512 + k0 + ps0], &Bs[b * 8192 + tid * 8]);
    gload16(&WT[(long)(n0 + ra1) * 512 + k0 + ps1], &Bs[b * 8192 + c1 * 8]);
  };

  stage(0, 0);
  stage(1, 32);
  stage(2, 64);

  for (int t = 0; t < 16; ++t) {
    const int cur = t & 3;
    if (t < 13) stage((t + 3) & 3, (t + 3) * 32);
    if (t == 0) {
      asm volatile("s_waitcnt vmcnt(12)" ::: "memory");
      __builtin_amdgcn_s_barrier();
    }
    bf16x8 af[8], bfr[4];
    #pragma unroll
    for (int n = 0; n < 4; n++)
      bfr[n] = *(const bf16x8*)&Bs[cur * 8192 + (wc * 64 + n * 16 + lr) * 32 + lkx];
    #pragma unroll
    for (int m = 0; m < 8; m++)
      af[m] = *(const bf16x8*)&As[cur * 8192 + (wr * 128 + m * 16 + lr) * 32 + lkx];
    __builtin_amdgcn_s_setprio(1);
    #pragma unroll
    for (int m = 0; m < 8; m++)
      #pragma unroll
      for (int n = 0; n < 4; n++)
        acc[m][n] = __builtin_amdgcn_mfma_f32_16x16x32_bf16(af[m], bfr[n], acc[m][n], 0, 0, 0);
    __builtin_amdgcn_s_setprio(0);
    if (t < 13)       asm volatile("s_waitcnt vmcnt(8)" ::: "memory");
    else if (t == 13) asm volatile("s_waitcnt vmcnt(4)" ::: "memory");
    else if (t == 14) asm volatile("s_waitcnt vmcnt(0)" ::: "memory");
    __builtin_amdgcn_s_barrier();
  }

  const int er = (lane >> 4) * 4, ec = lane & 15;
  if (nt < 4) {
    bf16* dst = (nt < 2) ? Qn : Kn;
    const int cb = (nt < 2) ? n0 : n0 - 512;
    #pragma unroll
    for (int m = 0; m < 8; m++) {
      const int row0 = m0 + wr * 128 + m * 16 + er;
      #pragma unroll
      for (int n = 0; n < 4; n++) {
        const int cw = wc * 64 + n * 16 + ec;
        const float bv = bias_all[n0 + cw];
        #pragma unroll
        for (int q = 0; q < 4; q++)
          dst[(long)(row0 + q) * 512 + cb + cw] = __float2bfloat16(acc[m][n][q] + bv);
      }
    }
  } else {
    // V tile: 4 passes over hd-quadrants; LDS transpose vt[64][264]; coalesced Vj stores
    bf16* vt = (bf16*)smem;
    const int r = m0 >> 8;
    const int hdbase = (nt - 4) * 256;
    #pragma unroll 1
    for (int p = 0; p < 4; ++p) {
      __syncthreads();
      if (wc == p) {
        #pragma unroll
        for (int m = 0; m < 8; m++) {
          const int rt0 = wr * 128 + m * 16 + er;
          #pragma unroll
          for (int n = 0; n < 4; n++) {
            const int ct = n * 16 + ec;
            const float bv = bias_all[n0 + p * 64 + ct];
            #pragma unroll
            for (int q = 0; q < 4; q++)
              vt[ct * 264 + rt0 + q] = __float2bfloat16(acc[m][n][q] + bv);
          }
        }
      }
      __syncthreads();
      #pragma unroll
      for (int cc = 0; cc < 4; cc++) {
        const int c = cc * 512 + tid;
        const int hl = c >> 5, tok8 = (c & 31) * 8;
        const uint4 v = *(const uint4*)&vt[hl * 264 + tok8];
        const int hd = hdbase + p * 64 + hl;
        const int h = hd >> 6, d = hd & 63;
        *(uint4*)&Vj[(long)h * HS + (long)(r * 64 + d) * 256 + tok8] = v;
      }
    }
  }
}

// ---------------- logits: splitK=4, z in [0,64). UNIFIED counted 4-buf pipeline.
// batch = z>>2 (0..7 head / 8..15 u-scaled), ks = z&3, 64 iters.
// uscale blocks scale the A-fragment at READ time: u index = d0 + (lane>>4)*8 + j
// (T2 read returns logical chunk lane>>4; d0 = (kk&1)*32).
__global__ __launch_bounds__(256)
void gemm_logits(const bf16* __restrict__ Qn, const bf16* __restrict__ Kn,
                 const float* __restrict__ u, float* __restrict__ part)
{
  __shared__ bf16 As[4][128 * 32];
  __shared__ bf16 Bs[4][128 * 32];
  __shared__ float us[64];
  const int tid = threadIdx.x, lane = tid & 63;
  const int wid = tid >> 6, wr = wid >> 1, wc = wid & 1;
  const int lr = lane & 15;
  const int lkx = ((lane >> 4) ^ ((lane >> 1) & 3)) * 8;
  const int z = blockIdx.z, batch = z >> 2, ks = z & 3, h = batch & 7;
  const bool uscale = batch >= 8;
  const int m0 = blockIdx.y * 128, n0 = blockIdx.x * 128;
  if (tid < 64) us[tid] = u[tid];
  __syncthreads();
  float ufa[8], ufb[8];   // correct logical-k u values for this lane's fragment
  const int gbase = (lane >> 4) * 8;
  #pragma unroll
  for (int j = 0; j < 8; j++) { ufa[j] = us[gbase + j]; ufb[j] = us[32 + gbase + j]; }
  const int c1 = tid + 256;
  const int ra0 = tid >> 2, ra1 = c1 >> 2;
  const int ps = swsrc(tid);
  f32x4 acc[4][4] = {};

  auto stage = [&](int b, int kk) {
    const int gk = ks * 2048 + kk * 32;
    const int r = gk >> 6, d0 = gk & 63;
    const long ab = (long)(r * 256 + m0) * 512 + h * 64 + d0;
    const long bb = (long)(r * 256 + n0) * 512 + h * 64 + d0;
    gload16(&Qn[ab + (long)ra0 * 512 + ps], &As[b][tid * 8]);
    gload16(&Qn[ab + (long)ra1 * 512 + ps], &As[b][c1 * 8]);
    gload16(&Kn[bb + (long)ra0 * 512 + ps], &Bs[b][tid * 8]);
    gload16(&Kn[bb + (long)ra1 * 512 + ps], &Bs[b][c1 * 8]);
  };

  stage(0, 0);
  stage(1, 1);
  stage(2, 2);

  for (int kk = 0; kk < 64; ++kk) {
    const int cur = kk & 3;
    if (kk < 61) stage((kk + 3) & 3, kk + 3);
    if (kk == 0) {
      asm volatile("s_waitcnt vmcnt(12)" ::: "memory");
      __builtin_amdgcn_s_barrier();
    }
    bf16x8 af[4], bfr[4];
    #pragma unroll
    for (int m = 0; m < 4; m++)
      af[m] = *(const bf16x8*)&As[cur][(wr * 64 + m * 16 + lr) * 32 + lkx];
    #pragma unroll
    for (int n = 0; n < 4; n++)
      bfr[n] = *(const bf16x8*)&Bs[cur][(wc * 64 + n * 16 + lr) * 32 + lkx];
    if (uscale) {
      const bool odd = (kk & 1) != 0;   // d0 = (kk&1)*32
      #pragma unroll
      for (int m = 0; m < 4; m++) {
        #pragma unroll
        for (int j = 0; j < 8; j++) {
          const unsigned short a_ = (unsigned short)af[m][j];
          const float f = __bfloat162float(*(const bf16*)&a_) * (odd ? ufb[j] : ufa[j]);
          const bf16 b_ = __float2bfloat16(f);
          af[m][j] = *(const short*)&b_;
        }
      }
    }
    __builtin_amdgcn_s_setprio(1);
    #pragma unroll
    for (int m = 0; m < 4; m++)
      #pragma unroll
      for (int n = 0; n < 4; n++)
        acc[m][n] = __builtin_amdgcn_mfma_f32_16x16x32_bf16(af[m], bfr[n], acc[m][n], 0, 0, 0);
    __builtin_amdgcn_s_setprio(0);
    if (kk < 61)       asm volatile("s_waitcnt vmcnt(8)" ::: "memory");
    else if (kk == 61) asm volatile("s_waitcnt vmcnt(4)" ::: "memory");
    else if (kk == 62) asm volatile("s_waitcnt vmcnt(0)" ::: "memory");
    __builtin_amdgcn_s_barrier();
  }

  float* C = part + (long)z * 65536;
  const int er = (lane >> 4) * 4, ec = lane & 15;
  #pragma unroll
  for (int m = 0; m < 4; m++)
    #pragma unroll
    for (int n = 0; n < 4; n++) {
      const int col = n0 + wc * 64 + n * 16 + ec;
      #pragma unroll
      for (int q = 0; q < 4; q++)
        C[(long)(m0 + wr * 64 + m * 16 + er + q) * 256 + col] = acc[m][n][q];
    }
}

// ---------------- ctx GEMM: A=Pb[h] (i x j), B=Vj[h] ((r,d) x j), K=256, counted 3-buf ----------------
__global__ __launch_bounds__(256)
void gemm_ctx(const bf16* __restrict__ Pb, const bf16* __restrict__ Vj,
              bf16* __restrict__ ctxb)
{
  __shared__ bf16 As[3][128 * 32];
  __shared__ bf16 Bs[3][128 * 32];
  const int tid = threadIdx.x, lane = tid & 63;
  const int wid = tid >> 6, wr = wid >> 1, wc = wid & 1;
  const int lr = lane & 15;
  const int lkx = ((lane >> 4) ^ ((lane >> 1) & 3)) * 8;
  const int m0 = blockIdx.y * 128, n0 = blockIdx.x * 128, h = blockIdx.z;
  const bf16* A = Pb + (long)h * 65536;
  const bf16* B = Vj + (long)h * HS;
  const int c1 = tid + 256;
  const int ra0 = tid >> 2, ra1 = c1 >> 2;
  const int ps = swsrc(tid);
  f32x4 acc[4][4] = {};

  auto stage = [&](int b, int k0) {
    gload16(&A[(long)(m0 + ra0) * 256 + k0 + ps], &As[b][tid * 8]);
    gload16(&A[(long)(m0 + ra1) * 256 + k0 + ps], &As[b][c1 * 8]);
    gload16(&B[(long)(n0 + ra0) * 256 + k0 + ps], &Bs[b][tid * 8]);
    gload16(&B[(long)(n0 + ra1) * 256 + k0 + ps], &Bs[b][c1 * 8]);
  };

  stage(0, 0);
  stage(1, 32);

  for (int t = 0; t < 8; ++t) {
    const int cur = t % 3;
    if (t < 6) {
      stage((t + 2) % 3, (t + 2) * 32);
      asm volatile("s_waitcnt vmcnt(8)" ::: "memory");
    } else if (t == 6) {
      asm volatile("s_waitcnt vmcnt(4)" ::: "memory");
    } else {
      asm volatile("s_waitcnt vmcnt(0)" ::: "memory");
    }
    __builtin_amdgcn_s_barrier();
    bf16x8 af[4], bfr[4];
    #pragma unroll
    for (int m = 0; m < 4; m++)
      af[m] = *(const bf16x8*)&As[cur][(wr * 64 + m * 16 + lr) * 32 + lkx];
    #pragma unroll
    for (int n = 0; n < 4; n++)
      bfr[n] = *(const bf16x8*)&Bs[cur][(wc * 64 + n * 16 + lr) * 32 + lkx];
    #pragma unroll
    for (int m = 0; m < 4; m++)
      #pragma unroll
      for (int n = 0; n < 4; n++)
        acc[m][n] = __builtin_amdgcn_mfma_f32_16x16x32_bf16(af[m], bfr[n], acc[m][n], 0, 0, 0);
    __builtin_amdgcn_s_barrier();
  }

  const int er = (lane >> 4) * 4, ec = lane & 15;
  #pragma unroll
  for (int m = 0; m < 4; m++) {
    const int i0 = m0 + wr * 64 + m * 16 + er;
    #pragma unroll
    for (int n = 0; n < 4; n++) {
      const int col = n0 + wc * 64 + n * 16 + ec;   // col = r*64 + d
      const int rr = col >> 6, dd = col & 63;
      #pragma unroll
      for (int q = 0; q < 4; q++)
        ctxb[(long)(rr * 256 + i0 + q) * 512 + h * 64 + dd] = __float2bfloat16(acc[m][n][q]);
    }
  }
}

// ---------------- output projection: 3-buffer counted-vmcnt, RAW barriers ----------------
__global__ __launch_bounds__(512)
void gemm_outp(const bf16* __restrict__ A, const bf16* __restrict__ B,
               float* __restrict__ C, const float* __restrict__ bias)
{
  __shared__ bf16 As[3][128 * 32];
  __shared__ bf16 Bs[3][256 * 32];
  const int tid = threadIdx.x, lane = tid & 63, wid = tid >> 6;
  const int wr = wid >> 2, wc = wid & 3;
  const int lr = lane & 15;
  const int lkx = ((lane >> 4) ^ ((lane >> 1) & 3)) * 8;
  const int m0 = blockIdx.y * 128, n0 = blockIdx.x * 256;
  const int ra = tid >> 2;
  const int cb1 = tid + 512;
  const int rb0 = tid >> 2, rb1 = cb1 >> 2;
  const int ps = swsrc(tid);
  f32x4 acc[4][4] = {};

  auto stage = [&](int b, int k0) {
    gload16(&A[(long)(m0 + ra) * 512 + k0 + ps], &As[b][tid * 8]);
    gload16(&B[(long)(n0 + rb0) * 512 + k0 + ps], &Bs[b][tid * 8]);
    gload16(&B[(long)(n0 + rb1) * 512 + k0 + ps], &Bs[b][cb1 * 8]);
  };

  stage(0, 0);
  stage(1, 32);

  for (int t = 0; t < 16; ++t) {
    const int cur = t % 3;
    if (t < 14) {
      stage((t + 2) % 3, (t + 2) * 32);
      asm volatile("s_waitcnt vmcnt(6)" ::: "memory");
    } else if (t == 14) {
      asm volatile("s_waitcnt vmcnt(3)" ::: "memory");
    } else {
      asm volatile("s_waitcnt vmcnt(0)" ::: "memory");
    }
    __builtin_amdgcn_s_barrier();
    bf16x8 af[4], bfr[4];
    #pragma unroll
    for (int m = 0; m < 4; m++)
      af[m] = *(const bf16x8*)&As[cur][(wr * 64 + m * 16 + lr) * 32 + lkx];
    #pragma unroll
    for (int n = 0; n < 4; n++)
      bfr[n] = *(const bf16x8*)&Bs[cur][(wc * 64 + n * 16 + lr) * 32 + lkx];
    #pragma unroll
    for (int m = 0; m < 4; m++)
      #pragma unroll
      for (int n = 0; n < 4; n++)
        acc[m][n] = __builtin_amdgcn_mfma_f32_16x16x32_bf16(af[m], bfr[n], acc[m][n], 0, 0, 0);
    __builtin_amdgcn_s_barrier();
  }

  const int er = (lane >> 4) * 4, ec = lane & 15;
  #pragma unroll
  for (int m = 0; m < 4; m++) {
    const int row0 = m0 + wr * 64 + m * 16 + er;
    #pragma unroll
    for (int n = 0; n < 4; n++) {
      const int col = n0 + wc * 64 + n * 16 + ec;
      const float bv = bias[col];
      #pragma unroll
      for (int q = 0; q < 4; q++)
        C[(long)(row0 + q) * 512 + col] = acc[m][n][q] + bv;
    }
  }
}

// ---------------- network-bias branch (u-slabs 32..63) ----------------
__global__ void k_bias(const float* __restrict__ part, const float* __restrict__ network,
                       const float* __restrict__ bq1, const float* __restrict__ Wk1,
                       float* __restrict__ net_bias)
{
  const int i = blockIdx.x, j = threadIdx.x;
  float c1 = 0.0f;
  #pragma unroll
  for (int c = 0; c < 8; c++) c1 += bq1[c] * Wk1[c];
  float s1 = 0.0f;
  const long ij = i * 256 + j;
  #pragma unroll
  for (int s = 32; s < 64; s++) s1 += part[(long)s * 65536 + ij];
  s1 = 0.125f * s1 + c1;
  const float4 nw = *(const float4*)&network[ij * 4];
  const float a0 = nw.x * s1, a1 = nw.y * s1, a2 = nw.z * s1, a3 = nw.w * s1;
  const float mx = fmaxf(fmaxf(a0, a1), fmaxf(a2, a3));
  const float e0 = expf(a0 - mx), e1 = expf(a1 - mx), e2 = expf(a2 - mx), e3 = expf(a3 - mx);
  const float inv = 1.0f / (e0 + e1 + e2 + e3);
  net_bias[ij] = (nw.x * e0 + nw.y * e1 + nw.z * e2 + nw.w * e3) * inv;
}

// ---------------- row softmax (sums 4 split-K partials), eye mask ----------------
__global__ void k_softmax(const float* __restrict__ part, const float* __restrict__ net_bias,
                          const float* __restrict__ l, float* __restrict__ out_probs,
                          bf16* __restrict__ Pb, float* __restrict__ out_l)
{
  const int i = blockIdx.x, h = blockIdx.y, j = threadIdx.x;
  const long ij = i * 256 + j;
  float w = 0.0f;
  #pragma unroll
  for (int ks = 0; ks < 4; ks++) w += part[(long)(h * 4 + ks) * 65536 + ij];
  w += l[h] * net_bias[ij];
  if (j == i) w = -1e9f;
  float m = w;
  #pragma unroll
  for (int o = 32; o; o >>= 1) m = fmaxf(m, __shfl_xor(m, o));
  __shared__ float red[4], red2[4];
  if ((j & 63) == 0) red[j >> 6] = m;
  __syncthreads();
  m = fmaxf(fmaxf(red[0], red[1]), fmaxf(red[2], red[3]));
  const float e = expf(w - m);
  float s = e;
  #pragma unroll
  for (int o = 32; o; o >>= 1) s += __shfl_xor(s, o);
  if ((j & 63) == 0) red2[j >> 6] = s;
  __syncthreads();
  s = red2[0] + red2[1] + red2[2] + red2[3];
  const float p = e / s;
  out_probs[(long)h * 65536 + ij] = p;
  Pb[(long)h * 65536 + ij] = __float2bfloat16(p);
  if (h == 0 && i == 0 && j < 8) out_l[j] = l[j];
}

extern "C" void kernel_launch(void* const* d_in, const int* in_sizes, int n_in,
                              void* d_out, int out_size, void* d_ws, size_t ws_size,
                              hipStream_t stream)
{
  const float* x   = (const float*)d_in[0];
  const float* net = (const float*)d_in[1];
  const float* Wq  = (const float*)d_in[2];
  const float* bq  = (const float*)d_in[3];
  const float* Wk  = (const float*)d_in[4];
  const float* bk  = (const float*)d_in[5];
  const float* Wv  = (const float*)d_in[6];
  const float* bv  = (const float*)d_in[7];
  const float* Wo  = (const float*)d_in[8];
  const float* bo  = (const float*)d_in[9];
  const float* Wq1 = (const float*)d_in[10];
  const float* bq1 = (const float*)d_in[11];
  const float* Wk1 = (const float*)d_in[12];
  const float* l   = (const float*)d_in[14];
  float* out = (float*)d_out;

  // d_out scratch: Qn [0,32MB), Kn [32,64MB) — dead before gemm_outp writes out.
  bf16* Qn = (bf16*)d_out;
  bf16* Kn = Qn + 16777216;

  char* ws = (char*)d_ws;
  size_t off = 0;
  auto alloc = [&](size_t bytes) { char* p = ws + off; off += (bytes + 255) & ~255ULL; return p; };
  bf16*  WT       = (bf16*)alloc(2048ULL * 512 * 2);    //  2 MB
  float* bias_all = (float*)alloc(2048 * 4);
  float* u        = (float*)alloc(64 * 4);
  bf16*  xb       = (bf16*)alloc(16777216ULL * 2);      // 32 MB -> part -> ctxb
  bf16*  Vj       = (bf16*)alloc(16777216ULL * 2);      // 32 MB (transposed V from qkv)
  float* net_bias = (float*)alloc(65536ULL * 4);        // 256 KB
  bf16*  Pb       = (bf16*)alloc(8ULL * 65536 * 2);     //  1 MB  (total ~67.5 MB)
  float* part     = (float*)xb;   // xb dead after gemm_qkv; 64 x 256KB = 16 MB
  bf16*  ctxb     = xb;           // part dead after k_bias/k_softmax

  const float scaling = (float)(0.125 / sqrt(128.0));  // D^-0.5 / sqrt(R)

  k_convert_x<<<8192, 256, 0, stream>>>(x, xb);
  k_prep_w<<<dim3(8, 8, 4), 256, 0, stream>>>(Wq, Wk, Wv, Wo, WT, scaling);
  k_prep_small<<<8, 256, 0, stream>>>(bq, bk, bv, bo, Wq1, Wk1, bias_all, u, scaling);

  gemm_qkv<<<768, 512, 0, stream>>>(xb, WT, bias_all, Qn, Kn, Vj);

  // 8 head batches (slabs 0..31) + 8 u-scaled batches (slabs 32..63), splitK=4
  gemm_logits<<<dim3(2, 2, 64), 256, 0, stream>>>(Qn, Kn, u, part);

  k_bias<<<256, 256, 0, stream>>>(part, net, bq1, Wk1, net_bias);
  k_softmax<<<dim3(256, 8, 1), 256, 0, stream>>>(part, net_bias, l,
                                                 out + 16777216, Pb, out + 17301504);

  gemm_ctx<<<dim3(64, 2, 8), 256, 0, stream>>>(Pb, Vj, ctxb);

  gemm_outp<<<dim3(2, 256, 1), 512, 0, stream>>>(ctxb, WT + 1536 * 512, out, bias_all + 1536);
}

// Round 16
// 189.613 us; speedup vs baseline: 1.0165x; 1.0016x over previous
//
#include <hip/hip_runtime.h>
#include <hip/hip_bf16.h>
#include <cmath>
#include <stdint.h>

using bf16 = __hip_bfloat16;
typedef __attribute__((ext_vector_type(8))) short bf16x8;
typedef __attribute__((ext_vector_type(4))) float f32x4;

// R=128, N=256, B=1, E=512, H=8, D=64, M=4
constexpr long HS = 2097152;  // per-head Vj size: (R*D) * N = 8192*256

// async 16B global -> LDS (linear dest: wave base + lane*16)
__device__ __forceinline__ void gload16(const bf16* g, bf16* l)
{
  __builtin_amdgcn_global_load_lds(
      (const __attribute__((address_space(1))) void*)g,
      (__attribute__((address_space(3))) void*)l,
      16, 0, 0);
}

// T2 swizzle: chunk c stores global slot (c&3)^((c>>3)&3) at linear slot (c&3).
// Read side: lane reads element offset ((lane>>4)^((lane>>1)&3))*8 of its row.
__device__ __forceinline__ int swsrc(int c) { return (((c & 3) ^ ((c >> 3) & 3)) * 8); }

// ---------------- merged setup: x convert | weight transpose | bias/u prep ----------------
__global__ __launch_bounds__(256)
void k_setup(const float* __restrict__ x, bf16* __restrict__ xb,
             const float* __restrict__ Wq, const float* __restrict__ Wk,
             const float* __restrict__ Wv, const float* __restrict__ Wo,
             const float* __restrict__ bq, const float* __restrict__ bk,
             const float* __restrict__ bv, const float* __restrict__ bo,
             const float* __restrict__ Wq1, const float* __restrict__ Wk1,
             bf16* __restrict__ WT, float* __restrict__ bias_all,
             float* __restrict__ u, float scaling)
{
  __shared__ float tile[64][68];
  const int bid = blockIdx.x, tid = threadIdx.x;
  if (bid < 8192) {
    // x fp32 -> bf16, 8 elems/thread
    const long idx = (long)bid * 256 + tid;
    const float4 f0 = *(const float4*)&x[idx * 8];
    const float4 f1 = *(const float4*)&x[idx * 8 + 4];
    alignas(16) bf16 t[8] = {
      __float2bfloat16(f0.x), __float2bfloat16(f0.y),
      __float2bfloat16(f0.z), __float2bfloat16(f0.w),
      __float2bfloat16(f1.x), __float2bfloat16(f1.y),
      __float2bfloat16(f1.z), __float2bfloat16(f1.w)};
    *(uint4*)&xb[idx * 8] = *(const uint4*)t;
  } else if (bid < 8448) {
    // WT[n][k] = W[k][n] (Q pre-scaled), 64x64 tile per block
    const int b2 = bid - 8192;
    const int sel = b2 >> 6, k0 = (b2 & 7) * 64, n0 = ((b2 >> 3) & 7) * 64;
    const float* W = sel == 0 ? Wq : sel == 1 ? Wk : sel == 2 ? Wv : Wo;
    const float sc = sel == 0 ? scaling : 1.0f;
    #pragma unroll
    for (int it = 0; it < 4; it++) {
      const int c = tid + it * 256;
      const int kk = c >> 4, nn4 = (c & 15) * 4;
      const float4 v = *(const float4*)&W[(long)(k0 + kk) * 512 + n0 + nn4];
      tile[kk][nn4] = v.x; tile[kk][nn4 + 1] = v.y;
      tile[kk][nn4 + 2] = v.z; tile[kk][nn4 + 3] = v.w;
    }
    __syncthreads();
    #pragma unroll
    for (int it = 0; it < 2; it++) {
      const int c = tid + it * 256;
      const int nn = c >> 3, k8 = (c & 7) * 8;
      alignas(16) bf16 t[8];
      #pragma unroll
      for (int jj = 0; jj < 8; jj++) t[jj] = __float2bfloat16(tile[k8 + jj][nn] * sc);
      *(uint4*)&WT[(long)(sel * 512 + n0 + nn) * 512 + k0 + k8] = *(const uint4*)t;
    }
  } else {
    const int idx = (bid - 8448) * 256 + tid;  // 0..2047
    const int s2 = idx >> 9, n2 = idx & 511;
    const float* b = s2 == 0 ? bq : s2 == 1 ? bk : s2 == 2 ? bv : bo;
    bias_all[idx] = b[n2] * (s2 == 0 ? scaling : 1.0f);
    if (idx < 64) {
      float s = 0.0f;
      #pragma unroll
      for (int c = 0; c < 8; c++) s += Wq1[idx * 8 + c] * Wk1[c];
      u[idx] = s;
    }
  }
}

// ---------------- QKV projection: 256x256 tile, 8 waves, 3-buf counted (r12-exact) ----------------
__global__ __launch_bounds__(512, 2)
void gemm_qkv(const bf16* __restrict__ xb, const bf16* __restrict__ WT,
              const float* __restrict__ bias_all,
              bf16* __restrict__ Qn, bf16* __restrict__ Kn, bf16* __restrict__ Vj)
{
  __shared__ __align__(16) unsigned short smem[49152];   // 96 KB: As 3x8192, Bs 3x8192
  bf16* As = (bf16*)smem;
  bf16* Bs = (bf16*)smem + 24576;
  const int tid = threadIdx.x, lane = tid & 63;
  const int wid = tid >> 6, wr = wid >> 2, wc = wid & 3;  // 2(m) x 4(n)
  const int lr = lane & 15;
  const int lkx = ((lane >> 4) ^ ((lane >> 1) & 3)) * 8;
  // XCD-aware bijective swizzle (768 = 8 * 96)
  const int flat = ((int)blockIdx.x & 7) * 96 + ((int)blockIdx.x >> 3);
  const int m0 = (flat / 6) * 256, nt = flat % 6, n0 = nt * 256;
  const int c1 = tid + 512;
  const int ra0 = tid >> 2, ra1 = c1 >> 2;
  const int ps0 = swsrc(tid), ps1 = swsrc(c1);
  f32x4 acc[8][4] = {};

  auto stage = [&](int b, int k0) {
    gload16(&xb[(long)(m0 + ra0) * 512 + k0 + ps0], &As[b * 8192 + tid * 8]);
    gload16(&xb[(long)(m0 + ra1) * 512 + k0 + ps1], &As[b * 8192 + c1 * 8]);
    gload16(&WT[(long)(n0 + ra0) * 512 + k0 + ps0], &Bs[b * 8192 + tid * 8]);
    gload16(&WT[(long)(n0 + ra1) * 512 + k0 + ps1], &Bs[b * 8192 + c1 * 8]);
  };

  stage(0, 0);
  stage(1, 32);

  for (int t = 0; t < 16; ++t) {
    const int cur = t % 3;
    if (t < 14) stage((t + 2) % 3, (t + 2) * 32);
    if (t == 0) {
      asm volatile("s_waitcnt vmcnt(8)" ::: "memory");
      __builtin_amdgcn_s_barrier();
    }
    bf16x8 af[8], bfr[4];
    #pragma unroll
    for (int n = 0; n < 4; n++)
      bfr[n] = *(const bf16x8*)&Bs[cur * 8192 + (wc * 64 + n * 16 + lr) * 32 + lkx];
    #pragma unroll
    for (int m = 0; m < 8; m++)
      af[m] = *(const bf16x8*)&As[cur * 8192 + (wr * 128 + m * 16 + lr) * 32 + lkx];
    #pragma unroll
    for (int m = 0; m < 8; m++)
      #pragma unroll
      for (int n = 0; n < 4; n++)
        acc[m][n] = __builtin_amdgcn_mfma_f32_16x16x32_bf16(af[m], bfr[n], acc[m][n], 0, 0, 0);
    if (t < 14)       asm volatile("s_waitcnt vmcnt(4)" ::: "memory");
    else if (t == 14) asm volatile("s_waitcnt vmcnt(0)" ::: "memory");
    __builtin_amdgcn_s_barrier();
  }

  const int er = (lane >> 4) * 4, ec = lane & 15;
  if (nt < 4) {
    bf16* dst = (nt < 2) ? Qn : Kn;
    const int cb = (nt < 2) ? n0 : n0 - 512;
    #pragma unroll
    for (int m = 0; m < 8; m++) {
      const int row0 = m0 + wr * 128 + m * 16 + er;
      #pragma unroll
      for (int n = 0; n < 4; n++) {
        const int cw = wc * 64 + n * 16 + ec;
        const float bv = bias_all[n0 + cw];
        #pragma unroll
        for (int q = 0; q < 4; q++)
          dst[(long)(row0 + q) * 512 + cb + cw] = __float2bfloat16(acc[m][n][q] + bv);
      }
    }
  } else {
    // V tile: 4 passes over hd-quadrants; LDS transpose vt[64][264]; coalesced Vj stores
    bf16* vt = (bf16*)smem;
    const int r = m0 >> 8;
    const int hdbase = (nt - 4) * 256;
    #pragma unroll 1
    for (int p = 0; p < 4; ++p) {
      __syncthreads();
      if (wc == p) {
        #pragma unroll
        for (int m = 0; m < 8; m++) {
          const int rt0 = wr * 128 + m * 16 + er;
          #pragma unroll
          for (int n = 0; n < 4; n++) {
            const int ct = n * 16 + ec;
            const float bv = bias_all[n0 + p * 64 + ct];
            #pragma unroll
            for (int q = 0; q < 4; q++)
              vt[ct * 264 + rt0 + q] = __float2bfloat16(acc[m][n][q] + bv);
          }
        }
      }
      __syncthreads();
      #pragma unroll
      for (int cc = 0; cc < 4; cc++) {
        const int c = cc * 512 + tid;
        const int hl = c >> 5, tok8 = (c & 31) * 8;
        const uint4 v = *(const uint4*)&vt[hl * 264 + tok8];
        const int hd = hdbase + p * 64 + hl;
        const int h = hd >> 6, d = hd & 63;
        *(uint4*)&Vj[(long)h * HS + (long)(r * 64 + d) * 256 + tok8] = v;
      }
    }
  }
}

// ---------------- logits: splitK=4, z in [0,64). UNIFIED counted 4-buf pipeline. ----------------
__global__ __launch_bounds__(256)
void gemm_logits(const bf16* __restrict__ Qn, const bf16* __restrict__ Kn,
                 const float* __restrict__ u, float* __restrict__ part)
{
  __shared__ bf16 As[4][128 * 32];
  __shared__ bf16 Bs[4][128 * 32];
  __shared__ float us[64];
  const int tid = threadIdx.x, lane = tid & 63;
  const int wid = tid >> 6, wr = wid >> 1, wc = wid & 1;
  const int lr = lane & 15;
  const int lkx = ((lane >> 4) ^ ((lane >> 1) & 3)) * 8;
  const int z = blockIdx.z, batch = z >> 2, ks = z & 3, h = batch & 7;
  const bool uscale = batch >= 8;
  const int m0 = blockIdx.y * 128, n0 = blockIdx.x * 128;
  if (tid < 64) us[tid] = u[tid];
  __syncthreads();
  float ufa[8], ufb[8];   // logical-k u values for this lane's fragment
  const int gbase = (lane >> 4) * 8;
  #pragma unroll
  for (int j = 0; j < 8; j++) { ufa[j] = us[gbase + j]; ufb[j] = us[32 + gbase + j]; }
  const int c1 = tid + 256;
  const int ra0 = tid >> 2, ra1 = c1 >> 2;
  const int ps = swsrc(tid);
  f32x4 acc[4][4] = {};

  auto stage = [&](int b, int kk) {
    const int gk = ks * 2048 + kk * 32;
    const int r = gk >> 6, d0 = gk & 63;
    const long ab = (long)(r * 256 + m0) * 512 + h * 64 + d0;
    const long bb = (long)(r * 256 + n0) * 512 + h * 64 + d0;
    gload16(&Qn[ab + (long)ra0 * 512 + ps], &As[b][tid * 8]);
    gload16(&Qn[ab + (long)ra1 * 512 + ps], &As[b][c1 * 8]);
    gload16(&Kn[bb + (long)ra0 * 512 + ps], &Bs[b][tid * 8]);
    gload16(&Kn[bb + (long)ra1 * 512 + ps], &Bs[b][c1 * 8]);
  };

  stage(0, 0);
  stage(1, 1);
  stage(2, 2);

  for (int kk = 0; kk < 64; ++kk) {
    const int cur = kk & 3;
    if (kk < 61) stage((kk + 3) & 3, kk + 3);
    if (kk == 0) {
      asm volatile("s_waitcnt vmcnt(12)" ::: "memory");
      __builtin_amdgcn_s_barrier();
    }
    bf16x8 af[4], bfr[4];
    #pragma unroll
    for (int m = 0; m < 4; m++)
      af[m] = *(const bf16x8*)&As[cur][(wr * 64 + m * 16 + lr) * 32 + lkx];
    #pragma unroll
    for (int n = 0; n < 4; n++)
      bfr[n] = *(const bf16x8*)&Bs[cur][(wc * 64 + n * 16 + lr) * 32 + lkx];
    if (uscale) {
      const bool odd = (kk & 1) != 0;   // d0 = (kk&1)*32
      #pragma unroll
      for (int m = 0; m < 4; m++) {
        #pragma unroll
        for (int j = 0; j < 8; j++) {
          const unsigned short a_ = (unsigned short)af[m][j];
          const float f = __bfloat162float(*(const bf16*)&a_) * (odd ? ufb[j] : ufa[j]);
          const bf16 b_ = __float2bfloat16(f);
          af[m][j] = *(const short*)&b_;
        }
      }
    }
    __builtin_amdgcn_s_setprio(1);
    #pragma unroll
    for (int m = 0; m < 4; m++)
      #pragma unroll
      for (int n = 0; n < 4; n++)
        acc[m][n] = __builtin_amdgcn_mfma_f32_16x16x32_bf16(af[m], bfr[n], acc[m][n], 0, 0, 0);
    __builtin_amdgcn_s_setprio(0);
    if (kk < 61)       asm volatile("s_waitcnt vmcnt(8)" ::: "memory");
    else if (kk == 61) asm volatile("s_waitcnt vmcnt(4)" ::: "memory");
    else if (kk == 62) asm volatile("s_waitcnt vmcnt(0)" ::: "memory");
    __builtin_amdgcn_s_barrier();
  }

  float* C = part + (long)z * 65536;
  const int er = (lane >> 4) * 4, ec = lane & 15;
  #pragma unroll
  for (int m = 0; m < 4; m++)
    #pragma unroll
    for (int n = 0; n < 4; n++) {
      const int col = n0 + wc * 64 + n * 16 + ec;
      #pragma unroll
      for (int q = 0; q < 4; q++)
        C[(long)(m0 + wr * 64 + m * 16 + er + q) * 256 + col] = acc[m][n][q];
    }
}

// ---------------- merged tail: net-bias + 8 head softmaxes, one pass over part ----------------
// grid 256 (i), 256 thr (j). slabs 0..31 head partials (h*4+ks), 32..63 u partials.
__global__ __launch_bounds__(256)
void k_tail(const float* __restrict__ part, const float* __restrict__ network,
            const float* __restrict__ bq1, const float* __restrict__ Wk1,
            const float* __restrict__ l, float* __restrict__ out_probs,
            bf16* __restrict__ Pb, float* __restrict__ out_l)
{
  const int i = blockIdx.x, j = threadIdx.x;
  const long ij = i * 256 + j;
  __shared__ float red[4], red2[4];

  float c1 = 0.0f;
  #pragma unroll
  for (int c = 0; c < 8; c++) c1 += bq1[c] * Wk1[c];
  float s1 = 0.0f;
  #pragma unroll
  for (int s = 32; s < 64; s++) s1 += part[(long)s * 65536 + ij];
  s1 = 0.125f * s1 + c1;
  const float4 nw = *(const float4*)&network[ij * 4];
  const float a0 = nw.x * s1, a1 = nw.y * s1, a2 = nw.z * s1, a3 = nw.w * s1;
  const float mx0 = fmaxf(fmaxf(a0, a1), fmaxf(a2, a3));
  const float e0 = expf(a0 - mx0), e1 = expf(a1 - mx0), e2 = expf(a2 - mx0), e3 = expf(a3 - mx0);
  const float nb = (nw.x * e0 + nw.y * e1 + nw.z * e2 + nw.w * e3) / (e0 + e1 + e2 + e3);

  #pragma unroll 1
  for (int h = 0; h < 8; h++) {
    float w = 0.0f;
    #pragma unroll
    for (int ks = 0; ks < 4; ks++) w += part[(long)(h * 4 + ks) * 65536 + ij];
    w += l[h] * nb;
    if (j == i) w = -1e9f;
    float m = w;
    #pragma unroll
    for (int o = 32; o; o >>= 1) m = fmaxf(m, __shfl_xor(m, o));
    if ((j & 63) == 0) red[j >> 6] = m;
    __syncthreads();
    m = fmaxf(fmaxf(red[0], red[1]), fmaxf(red[2], red[3]));
    const float e = expf(w - m);
    float s = e;
    #pragma unroll
    for (int o = 32; o; o >>= 1) s += __shfl_xor(s, o);
    if ((j & 63) == 0) red2[j >> 6] = s;
    __syncthreads();
    s = red2[0] + red2[1] + red2[2] + red2[3];
    const float p = e / s;
    out_probs[(long)h * 65536 + ij] = p;
    Pb[(long)h * 65536 + ij] = __float2bfloat16(p);
    __syncthreads();  // red/red2 reuse next h
  }
  if (i == 0 && j < 8) out_l[j] = l[j];
}

// ---------------- ctx GEMM: A=Pb[h] (i x j), B=Vj[h] ((r,d) x j), K=256, counted 3-buf ----------------
__global__ __launch_bounds__(256)
void gemm_ctx(const bf16* __restrict__ Pb, const bf16* __restrict__ Vj,
              bf16* __restrict__ ctxb)
{
  __shared__ bf16 As[3][128 * 32];
  __shared__ bf16 Bs[3][128 * 32];
  const int tid = threadIdx.x, lane = tid & 63;
  const int wid = tid >> 6, wr = wid >> 1, wc = wid & 1;
  const int lr = lane & 15;
  const int lkx = ((lane >> 4) ^ ((lane >> 1) & 3)) * 8;
  const int m0 = blockIdx.y * 128, n0 = blockIdx.x * 128, h = blockIdx.z;
  const bf16* A = Pb + (long)h * 65536;
  const bf16* B = Vj + (long)h * HS;
  const int c1 = tid + 256;
  const int ra0 = tid >> 2, ra1 = c1 >> 2;
  const int ps = swsrc(tid);
  f32x4 acc[4][4] = {};

  auto stage = [&](int b, int k0) {
    gload16(&A[(long)(m0 + ra0) * 256 + k0 + ps], &As[b][tid * 8]);
    gload16(&A[(long)(m0 + ra1) * 256 + k0 + ps], &As[b][c1 * 8]);
    gload16(&B[(long)(n0 + ra0) * 256 + k0 + ps], &Bs[b][tid * 8]);
    gload16(&B[(long)(n0 + ra1) * 256 + k0 + ps], &Bs[b][c1 * 8]);
  };

  stage(0, 0);
  stage(1, 32);

  for (int t = 0; t < 8; ++t) {
    const int cur = t % 3;
    if (t < 6) {
      stage((t + 2) % 3, (t + 2) * 32);
      asm volatile("s_waitcnt vmcnt(8)" ::: "memory");
    } else if (t == 6) {
      asm volatile("s_waitcnt vmcnt(4)" ::: "memory");
    } else {
      asm volatile("s_waitcnt vmcnt(0)" ::: "memory");
    }
    __builtin_amdgcn_s_barrier();
    bf16x8 af[4], bfr[4];
    #pragma unroll
    for (int m = 0; m < 4; m++)
      af[m] = *(const bf16x8*)&As[cur][(wr * 64 + m * 16 + lr) * 32 + lkx];
    #pragma unroll
    for (int n = 0; n < 4; n++)
      bfr[n] = *(const bf16x8*)&Bs[cur][(wc * 64 + n * 16 + lr) * 32 + lkx];
    #pragma unroll
    for (int m = 0; m < 4; m++)
      #pragma unroll
      for (int n = 0; n < 4; n++)
        acc[m][n] = __builtin_amdgcn_mfma_f32_16x16x32_bf16(af[m], bfr[n], acc[m][n], 0, 0, 0);
    __builtin_amdgcn_s_barrier();
  }

  const int er = (lane >> 4) * 4, ec = lane & 15;
  #pragma unroll
  for (int m = 0; m < 4; m++) {
    const int i0 = m0 + wr * 64 + m * 16 + er;
    #pragma unroll
    for (int n = 0; n < 4; n++) {
      const int col = n0 + wc * 64 + n * 16 + ec;   // col = r*64 + d
      const int rr = col >> 6, dd = col & 63;
      #pragma unroll
      for (int q = 0; q < 4; q++)
        ctxb[(long)(rr * 256 + i0 + q) * 512 + h * 64 + dd] = __float2bfloat16(acc[m][n][q]);
    }
  }
}

// ---------------- output projection: 3-buffer counted-vmcnt, RAW barriers ----------------
__global__ __launch_bounds__(512)
void gemm_outp(const bf16* __restrict__ A, const bf16* __restrict__ B,
               float* __restrict__ C, const float* __restrict__ bias)
{
  __shared__ bf16 As[3][128 * 32];
  __shared__ bf16 Bs[3][256 * 32];
  const int tid = threadIdx.x, lane = tid & 63, wid = tid >> 6;
  const int wr = wid >> 2, wc = wid & 3;
  const int lr = lane & 15;
  const int lkx = ((lane >> 4) ^ ((lane >> 1) & 3)) * 8;
  const int m0 = blockIdx.y * 128, n0 = blockIdx.x * 256;
  const int ra = tid >> 2;
  const int cb1 = tid + 512;
  const int rb0 = tid >> 2, rb1 = cb1 >> 2;
  const int ps = swsrc(tid);
  f32x4 acc[4][4] = {};

  auto stage = [&](int b, int k0) {
    gload16(&A[(long)(m0 + ra) * 512 + k0 + ps], &As[b][tid * 8]);
    gload16(&B[(long)(n0 + rb0) * 512 + k0 + ps], &Bs[b][tid * 8]);
    gload16(&B[(long)(n0 + rb1) * 512 + k0 + ps], &Bs[b][cb1 * 8]);
  };

  stage(0, 0);
  stage(1, 32);

  for (int t = 0; t < 16; ++t) {
    const int cur = t % 3;
    if (t < 14) {
      stage((t + 2) % 3, (t + 2) * 32);
      asm volatile("s_waitcnt vmcnt(6)" ::: "memory");
    } else if (t == 14) {
      asm volatile("s_waitcnt vmcnt(3)" ::: "memory");
    } else {
      asm volatile("s_waitcnt vmcnt(0)" ::: "memory");
    }
    __builtin_amdgcn_s_barrier();
    bf16x8 af[4], bfr[4];
    #pragma unroll
    for (int m = 0; m < 4; m++)
      af[m] = *(const bf16x8*)&As[cur][(wr * 64 + m * 16 + lr) * 32 + lkx];
    #pragma unroll
    for (int n = 0; n < 4; n++)
      bfr[n] = *(const bf16x8*)&Bs[cur][(wc * 64 + n * 16 + lr) * 32 + lkx];
    #pragma unroll
    for (int m = 0; m < 4; m++)
      #pragma unroll
      for (int n = 0; n < 4; n++)
        acc[m][n] = __builtin_amdgcn_mfma_f32_16x16x32_bf16(af[m], bfr[n], acc[m][n], 0, 0, 0);
    __builtin_amdgcn_s_barrier();
  }

  const int er = (lane >> 4) * 4, ec = lane & 15;
  #pragma unroll
  for (int m = 0; m < 4; m++) {
    const int row0 = m0 + wr * 64 + m * 16 + er;
    #pragma unroll
    for (int n = 0; n < 4; n++) {
      const int col = n0 + wc * 64 + n * 16 + ec;
      const float bv = bias[col];
      #pragma unroll
      for (int q = 0; q < 4; q++)
        C[(long)(row0 + q) * 512 + col] = acc[m][n][q] + bv;
    }
  }
}

extern "C" void kernel_launch(void* const* d_in, const int* in_sizes, int n_in,
                              void* d_out, int out_size, void* d_ws, size_t ws_size,
                              hipStream_t stream)
{
  const float* x   = (const float*)d_in[0];
  const float* net = (const float*)d_in[1];
  const float* Wq  = (const float*)d_in[2];
  const float* bq  = (const float*)d_in[3];
  const float* Wk  = (const float*)d_in[4];
  const float* bk  = (const float*)d_in[5];
  const float* Wv  = (const float*)d_in[6];
  const float* bv  = (const float*)d_in[7];
  const float* Wo  = (const float*)d_in[8];
  const float* bo  = (const float*)d_in[9];
  const float* Wq1 = (const float*)d_in[10];
  const float* bq1 = (const float*)d_in[11];
  const float* Wk1 = (const float*)d_in[12];
  const float* l   = (const float*)d_in[14];
  float* out = (float*)d_out;

  // d_out scratch: Qn [0,32MB), Kn [32,64MB) — dead before gemm_outp writes out.
  bf16* Qn = (bf16*)d_out;
  bf16* Kn = Qn + 16777216;

  char* ws = (char*)d_ws;
  size_t off = 0;
  auto alloc = [&](size_t bytes) { char* p = ws + off; off += (bytes + 255) & ~255ULL; return p; };
  bf16*  WT       = (bf16*)alloc(2048ULL * 512 * 2);    //  2 MB
  float* bias_all = (float*)alloc(2048 * 4);
  float* u        = (float*)alloc(64 * 4);
  bf16*  xb       = (bf16*)alloc(16777216ULL * 2);      // 32 MB -> part -> ctxb
  bf16*  Vj       = (bf16*)alloc(16777216ULL * 2);      // 32 MB (transposed V from qkv)
  bf16*  Pb       = (bf16*)alloc(8ULL * 65536 * 2);     //  1 MB  (total ~67 MB)
  float* part     = (float*)xb;   // xb dead after gemm_qkv; 64 x 256KB = 16 MB
  bf16*  ctxb     = xb;           // part dead after k_tail

  const float scaling = (float)(0.125 / sqrt(128.0));  // D^-0.5 / sqrt(R)

  k_setup<<<8456, 256, 0, stream>>>(x, xb, Wq, Wk, Wv, Wo, bq, bk, bv, bo,
                                    Wq1, Wk1, WT, bias_all, u, scaling);

  gemm_qkv<<<768, 512, 0, stream>>>(xb, WT, bias_all, Qn, Kn, Vj);

  // 8 head batches (slabs 0..31) + 8 u-scaled batches (slabs 32..63), splitK=4
  gemm_logits<<<dim3(2, 2, 64), 256, 0, stream>>>(Qn, Kn, u, part);

  k_tail<<<256, 256, 0, stream>>>(part, net, bq1, Wk1, l,
                                  out + 16777216, Pb, out + 17301504);

  gemm_ctx<<<dim3(64, 2, 8), 256, 0, stream>>>(Pb, Vj, ctxb);

  gemm_outp<<<dim3(2, 256, 1), 512, 0, stream>>>(ctxb, WT + 1536 * 512, out, bias_all + 1536);
}

// Round 17
// 186.750 us; speedup vs baseline: 1.0321x; 1.0153x over previous
//
#include <hip/hip_runtime.h>
#include <hip/hip_bf16.h>
#include <cmath>
#include <stdint.h>

using bf16 = __hip_bfloat16;
typedef __attribute__((ext_vector_type(8))) short bf16x8;
typedef __attribute__((ext_vector_type(4))) float f32x4;

// R=128, N=256, B=1, E=512, H=8, D=64, M=4
constexpr long HS = 2097152;  // per-head Vj size: (R*D) * N = 8192*256

// async 16B global -> LDS (linear dest: wave base + lane*16)
__device__ __forceinline__ void gload16(const bf16* g, bf16* l)
{
  __builtin_amdgcn_global_load_lds(
      (const __attribute__((address_space(1))) void*)g,
      (__attribute__((address_space(3))) void*)l,
      16, 0, 0);
}

// T2 swizzle: chunk c stores global slot (c&3)^((c>>3)&3) at linear slot (c&3).
// Read side: lane reads element offset ((lane>>4)^((lane>>1)&3))*8 of its row.
__device__ __forceinline__ int swsrc(int c) { return (((c & 3) ^ ((c >> 3) & 3)) * 8); }

// ---------------- merged setup: x convert | weight transpose | bias/u prep ----------------
__global__ __launch_bounds__(256)
void k_setup(const float* __restrict__ x, bf16* __restrict__ xb,
             const float* __restrict__ Wq, const float* __restrict__ Wk,
             const float* __restrict__ Wv, const float* __restrict__ Wo,
             const float* __restrict__ bq, const float* __restrict__ bk,
             const float* __restrict__ bv, const float* __restrict__ bo,
             const float* __restrict__ Wq1, const float* __restrict__ Wk1,
             bf16* __restrict__ WT, float* __restrict__ bias_all,
             float* __restrict__ u, float scaling)
{
  __shared__ float tile[64][68];
  const int bid = blockIdx.x, tid = threadIdx.x;
  if (bid < 8192) {
    const long idx = (long)bid * 256 + tid;
    const float4 f0 = *(const float4*)&x[idx * 8];
    const float4 f1 = *(const float4*)&x[idx * 8 + 4];
    alignas(16) bf16 t[8] = {
      __float2bfloat16(f0.x), __float2bfloat16(f0.y),
      __float2bfloat16(f0.z), __float2bfloat16(f0.w),
      __float2bfloat16(f1.x), __float2bfloat16(f1.y),
      __float2bfloat16(f1.z), __float2bfloat16(f1.w)};
    *(uint4*)&xb[idx * 8] = *(const uint4*)t;
  } else if (bid < 8448) {
    const int b2 = bid - 8192;
    const int sel = b2 >> 6, k0 = (b2 & 7) * 64, n0 = ((b2 >> 3) & 7) * 64;
    const float* W = sel == 0 ? Wq : sel == 1 ? Wk : sel == 2 ? Wv : Wo;
    const float sc = sel == 0 ? scaling : 1.0f;
    #pragma unroll
    for (int it = 0; it < 4; it++) {
      const int c = tid + it * 256;
      const int kk = c >> 4, nn4 = (c & 15) * 4;
      const float4 v = *(const float4*)&W[(long)(k0 + kk) * 512 + n0 + nn4];
      tile[kk][nn4] = v.x; tile[kk][nn4 + 1] = v.y;
      tile[kk][nn4 + 2] = v.z; tile[kk][nn4 + 3] = v.w;
    }
    __syncthreads();
    #pragma unroll
    for (int it = 0; it < 2; it++) {
      const int c = tid + it * 256;
      const int nn = c >> 3, k8 = (c & 7) * 8;
      alignas(16) bf16 t[8];
      #pragma unroll
      for (int jj = 0; jj < 8; jj++) t[jj] = __float2bfloat16(tile[k8 + jj][nn] * sc);
      *(uint4*)&WT[(long)(sel * 512 + n0 + nn) * 512 + k0 + k8] = *(const uint4*)t;
    }
  } else {
    const int idx = (bid - 8448) * 256 + tid;  // 0..2047
    const int s2 = idx >> 9, n2 = idx & 511;
    const float* b = s2 == 0 ? bq : s2 == 1 ? bk : s2 == 2 ? bv : bo;
    bias_all[idx] = b[n2] * (s2 == 0 ? scaling : 1.0f);
    if (idx < 64) {
      float s = 0.0f;
      #pragma unroll
      for (int c = 0; c < 8; c++) s += Wq1[idx * 8 + c] * Wk1[c];
      u[idx] = s;
    }
  }
}

// ---------------- QKV projection: 256x256 tile, 8 waves, 2-buf counted, 64KB (2 blocks/CU) ----------------
__global__ __launch_bounds__(512, 2)
void gemm_qkv(const bf16* __restrict__ xb, const bf16* __restrict__ WT,
              const float* __restrict__ bias_all,
              bf16* __restrict__ Qn, bf16* __restrict__ Kn, bf16* __restrict__ Vj)
{
  __shared__ __align__(16) unsigned short smem[32768];   // 64 KB: As 2x8192, Bs 2x8192
  bf16* As = (bf16*)smem;
  bf16* Bs = (bf16*)smem + 16384;
  const int tid = threadIdx.x, lane = tid & 63;
  const int wid = tid >> 6, wr = wid >> 2, wc = wid & 3;  // 2(m) x 4(n)
  const int lr = lane & 15;
  const int lkx = ((lane >> 4) ^ ((lane >> 1) & 3)) * 8;
  // XCD-aware bijective swizzle (768 = 8 * 96)
  const int flat = ((int)blockIdx.x & 7) * 96 + ((int)blockIdx.x >> 3);
  const int m0 = (flat / 6) * 256, nt = flat % 6, n0 = nt * 256;
  const int c1 = tid + 512;
  const int ra0 = tid >> 2, ra1 = c1 >> 2;
  const int ps0 = swsrc(tid), ps1 = swsrc(c1);
  f32x4 acc[8][4] = {};

  auto stage = [&](int b, int k0) {
    gload16(&xb[(long)(m0 + ra0) * 512 + k0 + ps0], &As[b * 8192 + tid * 8]);
    gload16(&xb[(long)(m0 + ra1) * 512 + k0 + ps1], &As[b * 8192 + c1 * 8]);
    gload16(&WT[(long)(n0 + ra0) * 512 + k0 + ps0], &Bs[b * 8192 + tid * 8]);
    gload16(&WT[(long)(n0 + ra1) * 512 + k0 + ps1], &Bs[b * 8192 + c1 * 8]);
  };

  stage(0, 0);

  for (int t = 0; t < 16; ++t) {
    const int cur = t & 1;
    // stage next tile into cur^1; its previous contents (tile t-1) were fully
    // consumed before the end-of-iter(t-1) barrier.
    if (t < 15) {
      stage(cur ^ 1, (t + 1) * 32);
      asm volatile("s_waitcnt vmcnt(4)" ::: "memory");  // own tile-t loads done
    } else {
      asm volatile("s_waitcnt vmcnt(0)" ::: "memory");
    }
    __builtin_amdgcn_s_barrier();                       // tile t resident for all waves
    bf16x8 af[8], bfr[4];
    #pragma unroll
    for (int n = 0; n < 4; n++)
      bfr[n] = *(const bf16x8*)&Bs[cur * 8192 + (wc * 64 + n * 16 + lr) * 32 + lkx];
    #pragma unroll
    for (int m = 0; m < 8; m++)
      af[m] = *(const bf16x8*)&As[cur * 8192 + (wr * 128 + m * 16 + lr) * 32 + lkx];
    #pragma unroll
    for (int m = 0; m < 8; m++)
      #pragma unroll
      for (int n = 0; n < 4; n++)
        acc[m][n] = __builtin_amdgcn_mfma_f32_16x16x32_bf16(af[m], bfr[n], acc[m][n], 0, 0, 0);
    __builtin_amdgcn_s_barrier();                       // all reads of cur done
  }

  const int er = (lane >> 4) * 4, ec = lane & 15;
  if (nt < 4) {
    bf16* dst = (nt < 2) ? Qn : Kn;
    const int cb = (nt < 2) ? n0 : n0 - 512;
    #pragma unroll
    for (int m = 0; m < 8; m++) {
      const int row0 = m0 + wr * 128 + m * 16 + er;
      #pragma unroll
      for (int n = 0; n < 4; n++) {
        const int cw = wc * 64 + n * 16 + ec;
        const float bv = bias_all[n0 + cw];
        #pragma unroll
        for (int q = 0; q < 4; q++)
          dst[(long)(row0 + q) * 512 + cb + cw] = __float2bfloat16(acc[m][n][q] + bv);
      }
    }
  } else {
    // V tile: 4 passes over hd-quadrants; LDS transpose vt[64][264] (33KB <= 64KB); coalesced Vj stores
    bf16* vt = (bf16*)smem;
    const int r = m0 >> 8;
    const int hdbase = (nt - 4) * 256;
    #pragma unroll 1
    for (int p = 0; p < 4; ++p) {
      __syncthreads();
      if (wc == p) {
        #pragma unroll
        for (int m = 0; m < 8; m++) {
          const int rt0 = wr * 128 + m * 16 + er;
          #pragma unroll
          for (int n = 0; n < 4; n++) {
            const int ct = n * 16 + ec;
            const float bv = bias_all[n0 + p * 64 + ct];
            #pragma unroll
            for (int q = 0; q < 4; q++)
              vt[ct * 264 + rt0 + q] = __float2bfloat16(acc[m][n][q] + bv);
          }
        }
      }
      __syncthreads();
      #pragma unroll
      for (int cc = 0; cc < 4; cc++) {
        const int c = cc * 512 + tid;
        const int hl = c >> 5, tok8 = (c & 31) * 8;
        const uint4 v = *(const uint4*)&vt[hl * 264 + tok8];
        const int hd = hdbase + p * 64 + hl;
        const int h = hd >> 6, d = hd & 63;
        *(uint4*)&Vj[(long)h * HS + (long)(r * 64 + d) * 256 + tok8] = v;
      }
    }
  }
}

// ---------------- logits: splitK=4, z in [0,64). UNIFIED counted 4-buf pipeline. ----------------
__global__ __launch_bounds__(256)
void gemm_logits(const bf16* __restrict__ Qn, const bf16* __restrict__ Kn,
                 const float* __restrict__ u, float* __restrict__ part)
{
  __shared__ bf16 As[4][128 * 32];
  __shared__ bf16 Bs[4][128 * 32];
  __shared__ float us[64];
  const int tid = threadIdx.x, lane = tid & 63;
  const int wid = tid >> 6, wr = wid >> 1, wc = wid & 1;
  const int lr = lane & 15;
  const int lkx = ((lane >> 4) ^ ((lane >> 1) & 3)) * 8;
  const int z = blockIdx.z, batch = z >> 2, ks = z & 3, h = batch & 7;
  const bool uscale = batch >= 8;
  const int m0 = blockIdx.y * 128, n0 = blockIdx.x * 128;
  if (tid < 64) us[tid] = u[tid];
  __syncthreads();
  float ufa[8], ufb[8];   // logical-k u values for this lane's fragment
  const int gbase = (lane >> 4) * 8;
  #pragma unroll
  for (int j = 0; j < 8; j++) { ufa[j] = us[gbase + j]; ufb[j] = us[32 + gbase + j]; }
  const int c1 = tid + 256;
  const int ra0 = tid >> 2, ra1 = c1 >> 2;
  const int ps = swsrc(tid);
  f32x4 acc[4][4] = {};

  auto stage = [&](int b, int kk) {
    const int gk = ks * 2048 + kk * 32;
    const int r = gk >> 6, d0 = gk & 63;
    const long ab = (long)(r * 256 + m0) * 512 + h * 64 + d0;
    const long bb = (long)(r * 256 + n0) * 512 + h * 64 + d0;
    gload16(&Qn[ab + (long)ra0 * 512 + ps], &As[b][tid * 8]);
    gload16(&Qn[ab + (long)ra1 * 512 + ps], &As[b][c1 * 8]);
    gload16(&Kn[bb + (long)ra0 * 512 + ps], &Bs[b][tid * 8]);
    gload16(&Kn[bb + (long)ra1 * 512 + ps], &Bs[b][c1 * 8]);
  };

  stage(0, 0);
  stage(1, 1);
  stage(2, 2);

  for (int kk = 0; kk < 64; ++kk) {
    const int cur = kk & 3;
    if (kk < 61) stage((kk + 3) & 3, kk + 3);
    if (kk == 0) {
      asm volatile("s_waitcnt vmcnt(12)" ::: "memory");
      __builtin_amdgcn_s_barrier();
    }
    bf16x8 af[4], bfr[4];
    #pragma unroll
    for (int m = 0; m < 4; m++)
      af[m] = *(const bf16x8*)&As[cur][(wr * 64 + m * 16 + lr) * 32 + lkx];
    #pragma unroll
    for (int n = 0; n < 4; n++)
      bfr[n] = *(const bf16x8*)&Bs[cur][(wc * 64 + n * 16 + lr) * 32 + lkx];
    if (uscale) {
      const bool odd = (kk & 1) != 0;   // d0 = (kk&1)*32
      #pragma unroll
      for (int m = 0; m < 4; m++) {
        #pragma unroll
        for (int j = 0; j < 8; j++) {
          const unsigned short a_ = (unsigned short)af[m][j];
          const float f = __bfloat162float(*(const bf16*)&a_) * (odd ? ufb[j] : ufa[j]);
          const bf16 b_ = __float2bfloat16(f);
          af[m][j] = *(const short*)&b_;
        }
      }
    }
    __builtin_amdgcn_s_setprio(1);
    #pragma unroll
    for (int m = 0; m < 4; m++)
      #pragma unroll
      for (int n = 0; n < 4; n++)
        acc[m][n] = __builtin_amdgcn_mfma_f32_16x16x32_bf16(af[m], bfr[n], acc[m][n], 0, 0, 0);
    __builtin_amdgcn_s_setprio(0);
    if (kk < 61)       asm volatile("s_waitcnt vmcnt(8)" ::: "memory");
    else if (kk == 61) asm volatile("s_waitcnt vmcnt(4)" ::: "memory");
    else if (kk == 62) asm volatile("s_waitcnt vmcnt(0)" ::: "memory");
    __builtin_amdgcn_s_barrier();
  }

  float* C = part + (long)z * 65536;
  const int er = (lane >> 4) * 4, ec = lane & 15;
  #pragma unroll
  for (int m = 0; m < 4; m++)
    #pragma unroll
    for (int n = 0; n < 4; n++) {
      const int col = n0 + wc * 64 + n * 16 + ec;
      #pragma unroll
      for (int q = 0; q < 4; q++)
        C[(long)(m0 + wr * 64 + m * 16 + er + q) * 256 + col] = acc[m][n][q];
    }
}

// ---------------- merged tail: net-bias + 8 head softmaxes ----------------
__global__ __launch_bounds__(256)
void k_tail(const float* __restrict__ part, const float* __restrict__ network,
            const float* __restrict__ bq1, const float* __restrict__ Wk1,
            const float* __restrict__ l, float* __restrict__ out_probs,
            bf16* __restrict__ Pb, float* __restrict__ out_l)
{
  const int i = blockIdx.x, j = threadIdx.x;
  const long ij = i * 256 + j;
  __shared__ float red[4], red2[4];

  float c1 = 0.0f;
  #pragma unroll
  for (int c = 0; c < 8; c++) c1 += bq1[c] * Wk1[c];
  float s1 = 0.0f;
  #pragma unroll
  for (int s = 32; s < 64; s++) s1 += part[(long)s * 65536 + ij];
  s1 = 0.125f * s1 + c1;
  const float4 nw = *(const float4*)&network[ij * 4];
  const float a0 = nw.x * s1, a1 = nw.y * s1, a2 = nw.z * s1, a3 = nw.w * s1;
  const float mx0 = fmaxf(fmaxf(a0, a1), fmaxf(a2, a3));
  const float e0 = expf(a0 - mx0), e1 = expf(a1 - mx0), e2 = expf(a2 - mx0), e3 = expf(a3 - mx0);
  const float nb = (nw.x * e0 + nw.y * e1 + nw.z * e2 + nw.w * e3) / (e0 + e1 + e2 + e3);

  #pragma unroll 1
  for (int h = 0; h < 8; h++) {
    float w = 0.0f;
    #pragma unroll
    for (int ks = 0; ks < 4; ks++) w += part[(long)(h * 4 + ks) * 65536 + ij];
    w += l[h] * nb;
    if (j == i) w = -1e9f;
    float m = w;
    #pragma unroll
    for (int o = 32; o; o >>= 1) m = fmaxf(m, __shfl_xor(m, o));
    if ((j & 63) == 0) red[j >> 6] = m;
    __syncthreads();
    m = fmaxf(fmaxf(red[0], red[1]), fmaxf(red[2], red[3]));
    const float e = expf(w - m);
    float s = e;
    #pragma unroll
    for (int o = 32; o; o >>= 1) s += __shfl_xor(s, o);
    if ((j & 63) == 0) red2[j >> 6] = s;
    __syncthreads();
    s = red2[0] + red2[1] + red2[2] + red2[3];
    const float p = e / s;
    out_probs[(long)h * 65536 + ij] = p;
    Pb[(long)h * 65536 + ij] = __float2bfloat16(p);
    __syncthreads();
  }
  if (i == 0 && j < 8) out_l[j] = l[j];
}

// ---------------- ctx GEMM: A=Pb[h] (i x j), B=Vj[h] ((r,d) x j), K=256, counted 3-buf ----------------
__global__ __launch_bounds__(256)
void gemm_ctx(const bf16* __restrict__ Pb, const bf16* __restrict__ Vj,
              bf16* __restrict__ ctxb)
{
  __shared__ bf16 As[3][128 * 32];
  __shared__ bf16 Bs[3][128 * 32];
  const int tid = threadIdx.x, lane = tid & 63;
  const int wid = tid >> 6, wr = wid >> 1, wc = wid & 1;
  const int lr = lane & 15;
  const int lkx = ((lane >> 4) ^ ((lane >> 1) & 3)) * 8;
  const int m0 = blockIdx.y * 128, n0 = blockIdx.x * 128, h = blockIdx.z;
  const bf16* A = Pb + (long)h * 65536;
  const bf16* B = Vj + (long)h * HS;
  const int c1 = tid + 256;
  const int ra0 = tid >> 2, ra1 = c1 >> 2;
  const int ps = swsrc(tid);
  f32x4 acc[4][4] = {};

  auto stage = [&](int b, int k0) {
    gload16(&A[(long)(m0 + ra0) * 256 + k0 + ps], &As[b][tid * 8]);
    gload16(&A[(long)(m0 + ra1) * 256 + k0 + ps], &As[b][c1 * 8]);
    gload16(&B[(long)(n0 + ra0) * 256 + k0 + ps], &Bs[b][tid * 8]);
    gload16(&B[(long)(n0 + ra1) * 256 + k0 + ps], &Bs[b][c1 * 8]);
  };

  stage(0, 0);
  stage(1, 32);

  for (int t = 0; t < 8; ++t) {
    const int cur = t % 3;
    if (t < 6) {
      stage((t + 2) % 3, (t + 2) * 32);
      asm volatile("s_waitcnt vmcnt(8)" ::: "memory");
    } else if (t == 6) {
      asm volatile("s_waitcnt vmcnt(4)" ::: "memory");
    } else {
      asm volatile("s_waitcnt vmcnt(0)" ::: "memory");
    }
    __builtin_amdgcn_s_barrier();
    bf16x8 af[4], bfr[4];
    #pragma unroll
    for (int m = 0; m < 4; m++)
      af[m] = *(const bf16x8*)&As[cur][(wr * 64 + m * 16 + lr) * 32 + lkx];
    #pragma unroll
    for (int n = 0; n < 4; n++)
      bfr[n] = *(const bf16x8*)&Bs[cur][(wc * 64 + n * 16 + lr) * 32 + lkx];
    #pragma unroll
    for (int m = 0; m < 4; m++)
      #pragma unroll
      for (int n = 0; n < 4; n++)
        acc[m][n] = __builtin_amdgcn_mfma_f32_16x16x32_bf16(af[m], bfr[n], acc[m][n], 0, 0, 0);
    __builtin_amdgcn_s_barrier();
  }

  const int er = (lane >> 4) * 4, ec = lane & 15;
  #pragma unroll
  for (int m = 0; m < 4; m++) {
    const int i0 = m0 + wr * 64 + m * 16 + er;
    #pragma unroll
    for (int n = 0; n < 4; n++) {
      const int col = n0 + wc * 64 + n * 16 + ec;   // col = r*64 + d
      const int rr = col >> 6, dd = col & 63;
      #pragma unroll
      for (int q = 0; q < 4; q++)
        ctxb[(long)(rr * 256 + i0 + q) * 512 + h * 64 + dd] = __float2bfloat16(acc[m][n][q]);
    }
  }
}

// ---------------- output projection: 3-buffer counted-vmcnt, RAW barriers ----------------
__global__ __launch_bounds__(512)
void gemm_outp(const bf16* __restrict__ A, const bf16* __restrict__ B,
               float* __restrict__ C, const float* __restrict__ bias)
{
  __shared__ bf16 As[3][128 * 32];
  __shared__ bf16 Bs[3][256 * 32];
  const int tid = threadIdx.x, lane = tid & 63, wid = tid >> 6;
  const int wr = wid >> 2, wc = wid & 3;
  const int lr = lane & 15;
  const int lkx = ((lane >> 4) ^ ((lane >> 1) & 3)) * 8;
  const int m0 = blockIdx.y * 128, n0 = blockIdx.x * 256;
  const int ra = tid >> 2;
  const int cb1 = tid + 512;
  const int rb0 = tid >> 2, rb1 = cb1 >> 2;
  const int ps = swsrc(tid);
  f32x4 acc[4][4] = {};

  auto stage = [&](int b, int k0) {
    gload16(&A[(long)(m0 + ra) * 512 + k0 + ps], &As[b][tid * 8]);
    gload16(&B[(long)(n0 + rb0) * 512 + k0 + ps], &Bs[b][tid * 8]);
    gload16(&B[(long)(n0 + rb1) * 512 + k0 + ps], &Bs[b][cb1 * 8]);
  };

  stage(0, 0);
  stage(1, 32);

  for (int t = 0; t < 16; ++t) {
    const int cur = t % 3;
    if (t < 14) {
      stage((t + 2) % 3, (t + 2) * 32);
      asm volatile("s_waitcnt vmcnt(6)" ::: "memory");
    } else if (t == 14) {
      asm volatile("s_waitcnt vmcnt(3)" ::: "memory");
    } else {
      asm volatile("s_waitcnt vmcnt(0)" ::: "memory");
    }
    __builtin_amdgcn_s_barrier();
    bf16x8 af[4], bfr[4];
    #pragma unroll
    for (int m = 0; m < 4; m++)
      af[m] = *(const bf16x8*)&As[cur][(wr * 64 + m * 16 + lr) * 32 + lkx];
    #pragma unroll
    for (int n = 0; n < 4; n++)
      bfr[n] = *(const bf16x8*)&Bs[cur][(wc * 64 + n * 16 + lr) * 32 + lkx];
    #pragma unroll
    for (int m = 0; m < 4; m++)
      #pragma unroll
      for (int n = 0; n < 4; n++)
        acc[m][n] = __builtin_amdgcn_mfma_f32_16x16x32_bf16(af[m], bfr[n], acc[m][n], 0, 0, 0);
    __builtin_amdgcn_s_barrier();
  }

  const int er = (lane >> 4) * 4, ec = lane & 15;
  #pragma unroll
  for (int m = 0; m < 4; m++) {
    const int row0 = m0 + wr * 64 + m * 16 + er;
    #pragma unroll
    for (int n = 0; n < 4; n++) {
      const int col = n0 + wc * 64 + n * 16 + ec;
      const float bv = bias[col];
      #pragma unroll
      for (int q = 0; q < 4; q++)
        C[(long)(row0 + q) * 512 + col] = acc[m][n][q] + bv;
    }
  }
}

extern "C" void kernel_launch(void* const* d_in, const int* in_sizes, int n_in,
                              void* d_out, int out_size, void* d_ws, size_t ws_size,
                              hipStream_t stream)
{
  const float* x   = (const float*)d_in[0];
  const float* net = (const float*)d_in[1];
  const float* Wq  = (const float*)d_in[2];
  const float* bq  = (const float*)d_in[3];
  const float* Wk  = (const float*)d_in[4];
  const float* bk  = (const float*)d_in[5];
  const float* Wv  = (const float*)d_in[6];
  const float* bv  = (const float*)d_in[7];
  const float* Wo  = (const float*)d_in[8];
  const float* bo  = (const float*)d_in[9];
  const float* Wq1 = (const float*)d_in[10];
  const float* bq1 = (const float*)d_in[11];
  const float* Wk1 = (const float*)d_in[12];
  const float* l   = (const float*)d_in[14];
  float* out = (float*)d_out;

  // d_out scratch: Qn [0,32MB), Kn [32,64MB) — dead before gemm_outp writes out.
  bf16* Qn = (bf16*)d_out;
  bf16* Kn = Qn + 16777216;

  char* ws = (char*)d_ws;
  size_t off = 0;
  auto alloc = [&](size_t bytes) { char* p = ws + off; off += (bytes + 255) & ~255ULL; return p; };
  bf16*  WT       = (bf16*)alloc(2048ULL * 512 * 2);    //  2 MB
  float* bias_all = (float*)alloc(2048 * 4);
  float* u        = (float*)alloc(64 * 4);
  bf16*  xb       = (bf16*)alloc(16777216ULL * 2);      // 32 MB -> part -> ctxb
  bf16*  Vj       = (bf16*)alloc(16777216ULL * 2);      // 32 MB (transposed V from qkv)
  bf16*  Pb       = (bf16*)alloc(8ULL * 65536 * 2);     //  1 MB  (total ~67 MB)
  float* part     = (float*)xb;   // xb dead after gemm_qkv; 64 x 256KB = 16 MB
  bf16*  ctxb     = xb;           // part dead after k_tail

  const float scaling = (float)(0.125 / sqrt(128.0));  // D^-0.5 / sqrt(R)

  k_setup<<<8456, 256, 0, stream>>>(x, xb, Wq, Wk, Wv, Wo, bq, bk, bv, bo,
                                    Wq1, Wk1, WT, bias_all, u, scaling);

  gemm_qkv<<<768, 512, 0, stream>>>(xb, WT, bias_all, Qn, Kn, Vj);

  // 8 head batches (slabs 0..31) + 8 u-scaled batches (slabs 32..63), splitK=4
  gemm_logits<<<dim3(2, 2, 64), 256, 0, stream>>>(Qn, Kn, u, part);

  k_tail<<<256, 256, 0, stream>>>(part, net, bq1, Wk1, l,
                                  out + 16777216, Pb, out + 17301504);

  gemm_ctx<<<dim3(64, 2, 8), 256, 0, stream>>>(Pb, Vj, ctxb);

  gemm_outp<<<dim3(2, 256, 1), 512, 0, stream>>>(ctxb, WT + 1536 * 512, out, bias_all + 1536);
}